// Round 1
// 6892.543 us; speedup vs baseline: 1.0676x; 1.0676x over previous
//
#include <hip/hip_runtime.h>
#include <cstdint>
#include <cstddef>

// ===========================================================================
// VQ-VAE encoder: 6x conv1d(k=4) + BN(train) + relu chain, then VQ (argmin,
// EMA codebook update). B=32, T=4096, D=256, K=1024.
//
// R3: conv2..6 and vq_argmin moved from fp32 vector SGEMM (74 TF, MfmaUtil=0)
// to split-fp16 MFMA (v_mfma_f32_16x16x32_f16). Each fp32 value is split
// a = a_hi + a_lo (fp16 halves, lo pre-scaled x2048 to avoid subnormals);
// C = Ahi*Bhi (acc1) + (Ahi*Blo' + Alo'*Bhi)/2048 (acc2). Per-product error
// ~2^-22 relative == fp32-chain reorder noise, so id decisions stay in the
// same class as the fp32 kernel. K reordered to ci*4+tap (== native [i][k]
// weight layout, so weight prep is elementwise) making tap re-reads of X
// temporally L2-local.
// ===========================================================================

typedef _Float16 half8 __attribute__((ext_vector_type(8)));
typedef float f32x4 __attribute__((ext_vector_type(4)));

#define MFMA16(a, b, c) __builtin_amdgcn_mfma_f32_16x16x32_f16((a), (b), (c), 0, 0, 0)

__device__ __forceinline__ void splitf(float v, _Float16& h, _Float16& l)
{
    _Float16 hh = (_Float16)v;
    h = hh;
    l = (_Float16)((v - (float)hh) * 2048.0f);
}

// ---------------------------------------------------------------------------
// conv1: x (32,4096,12) -> Y (32,4097,256), pad=2, k=4. (fp32; 3.2 GFLOP)
// ---------------------------------------------------------------------------
__global__ __launch_bounds__(256)
void conv1_kernel(const float* __restrict__ x, const float* __restrict__ w1,
                  const float* __restrict__ b1, float* __restrict__ Y)
{
    const int b  = blockIdx.y;
    const int t0 = blockIdx.x * 32;
    const int oc = threadIdx.x;
    __shared__ float xl[35 * 12];
    for (int idx = threadIdx.x; idx < 420; idx += 256) {
        int tt = t0 - 2 + idx / 12;
        int i  = idx % 12;
        xl[idx] = (tt >= 0 && tt < 4096) ? x[((size_t)b * 4096 + tt) * 12 + i] : 0.f;
    }
    float w[48];
#pragma unroll
    for (int q = 0; q < 12; q++)
        *(float4*)&w[q * 4] = *(const float4*)(w1 + (size_t)oc * 48 + q * 4);
    __syncthreads();
    const float bias = b1[oc];
    for (int dt = 0; dt < 32; dt++) {
        int t = t0 + dt;
        if (t >= 4097) break;
        float a = bias;
#pragma unroll
        for (int i = 0; i < 12; i++)
#pragma unroll
            for (int k = 0; k < 4; k++)
                a = fmaf(xl[(dt + k) * 12 + i], w[i * 4 + k], a);
        Y[((size_t)b * 4097 + t) * 256 + oc] = a;
    }
}

// ---------------------------------------------------------------------------
// Deterministic BN stats.
// ---------------------------------------------------------------------------
__global__ __launch_bounds__(256)
void bn_partial(const float* __restrict__ Y, int M, float* __restrict__ part)
{
    const int j = blockIdx.x;   // 0..255
    const int c = threadIdx.x;  // channel
    const int chunk = (M + 255) / 256;
    int r0 = j * chunk;
    int r1 = r0 + chunk; if (r1 > M) r1 = M;
    float s = 0.f, s2 = 0.f;
    for (int r = r0; r < r1; r++) {
        float v = Y[((size_t)r << 8) + c];
        s += v;
        s2 = fmaf(v, v, s2);
    }
    part[j * 256 + c]         = s;
    part[65536 + j * 256 + c] = s2;
}

__global__ __launch_bounds__(256)
void bn_finalize(const float* __restrict__ part, const float* __restrict__ g,
                 const float* __restrict__ be, float invM, float* __restrict__ scsh)
{
    const int c = threadIdx.x;
    float s = 0.f, s2 = 0.f;
    for (int j = 0; j < 256; j++) {
        s  += part[j * 256 + c];
        s2 += part[65536 + j * 256 + c];
    }
    float mean = s * invM;
    float var  = fmaf(s2, invM, -mean * mean);
    float sc   = g[c] * rsqrtf(var + 1e-5f);
    scsh[c]       = sc;
    scsh[256 + c] = fmaf(-mean, sc, be[c]);
}

// ---------------------------------------------------------------------------
// Elementwise fp32 -> (hi, lo*2048) fp16 split. Used for conv weights
// (layout [o][ci*4+tap] == native [o][i][k], 262144 elems) and codebook
// ([code][d], 262144 elems).
// ---------------------------------------------------------------------------
__global__ __launch_bounds__(256)
void prep_split(const float* __restrict__ src, _Float16* __restrict__ hi,
                _Float16* __restrict__ lo)
{
    int idx = blockIdx.x * 256 + threadIdx.x;
    float v = src[idx];
    _Float16 h, l;
    splitf(v, h, l);
    hi[idx] = h;
    lo[idx] = l;
}

// per-code squared norms (fp32 exact)
__global__ __launch_bounds__(256)
void prep_cnorm(const float* __restrict__ cb, float* __restrict__ cnorm)
{
    const int k = blockIdx.x;   // 1024
    const int d = threadIdx.x;  // 256
    float v = cb[((size_t)k << 8) + d];
    __shared__ float sm[256];
    sm[d] = v * v;
    __syncthreads();
    for (int off = 128; off > 0; off >>= 1) {
        if (d < off) sm[d] += sm[d + off];
        __syncthreads();
    }
    if (d == 0) cnorm[k] = sm[0];
}

// ---------------------------------------------------------------------------
// conv2..6 as split-fp16 MFMA GEMM, 128x128 tile, BK=32, 4 waves of
// (32 rows x 128 cols), fused BN(prev)+relu+split on A-stage.
// K index: k = ci*4 + tap  => A[m][k] = relu(bn(X[b][t+tap-PAD][ci])).
// LDS: [row][k] fp16, XOR-swizzled half_idx ^= (row&7)<<3 (bank-conflict-free
// for both the quad-per-row staging writes and the fragment b128 reads).
// ---------------------------------------------------------------------------
template<int T_IN, int T_OUT, int PAD>
__global__ __launch_bounds__(256)
void conv_gemm_mfma(const float* __restrict__ X, const float* __restrict__ scsh,
                    const _Float16* __restrict__ Whi, const _Float16* __restrict__ Wlo,
                    const float* __restrict__ bias, float* __restrict__ Y)
{
    constexpr int M = 32 * T_OUT;
    __shared__ _Float16 AsH[4096], AsL[4096], BsH[4096], BsL[4096];

    const int tid  = threadIdx.x;
    const int lane = tid & 63;
    const int wv   = tid >> 6;     // wave 0..3 -> rows 32*wv .. 32*wv+31
    const int fr   = lane & 15;    // frag row (A) / frag col (B,C)
    const int kgf  = lane >> 4;    // frag k-group (8 halves)
    const int m0 = blockIdx.y * 128;
    const int n0 = blockIdx.x * 128;

    // fragment LDS offsets (in halves); (32wv+16i+fr)&7 == fr&7
    const int haBase = wv * 1024 + ((fr * 32 + kgf * 8) ^ ((fr & 7) << 3));
    const int hbBase = (fr * 32 + kgf * 8) ^ ((fr & 7) << 3);

    // staging tasks: id = tid + 256*u ; row = id>>2 ; kg = id&3  (quad-per-row)
    const int skg = tid & 3;
    int srow[2];
    srow[0] = tid >> 2;
    srow[1] = 64 + (tid >> 2);
    int wOff[2];
    int tb[2], tt[2];
    bool mok[2];
#pragma unroll
    for (int u = 0; u < 2; u++) {
        int r = srow[u];
        wOff[u] = (r * 32 + skg * 8) ^ ((r & 7) << 3);
        int m = m0 + r;
        mok[u] = (m < M);
        int b;
        if (T_OUT == 4096) b = m >> 12;
        else               b = (m - (m >> 12)) >> 12;   // m/4097 for m < 2^17
        tb[u] = b;
        tt[u] = m - b * T_OUT;
    }

    f32x4 acc1[2][8], acc2[2][8];
#pragma unroll
    for (int i = 0; i < 2; i++)
#pragma unroll
        for (int j = 0; j < 8; j++) {
            acc1[i][j] = (f32x4){0.f, 0.f, 0.f, 0.f};
            acc2[i][j] = (f32x4){0.f, 0.f, 0.f, 0.f};
        }

    for (int kk0 = 0; kk0 < 1024; kk0 += 32) {
        __syncthreads();
        // ---- stage A (BN+relu+split) ----
#pragma unroll
        for (int u = 0; u < 2; u++) {
            const int cib = (kk0 >> 2) + (skg << 1);     // 2 channels per task
            const float sc0 = scsh[cib],       sc1 = scsh[cib + 1];
            const float sh0 = scsh[256 + cib], sh1 = scsh[256 + cib + 1];
            const int b = tb[u], t = tt[u];
            float v[8];
#pragma unroll
            for (int tap = 0; tap < 4; tap++) {
                int st = t + tap - PAD;
                if (mok[u] && st >= 0 && st < T_IN) {
                    float2 xv = *(const float2*)(X + (((size_t)b * T_IN + st) << 8) + cib);
                    v[tap]     = fmaxf(fmaf(xv.x, sc0, sh0), 0.f);
                    v[4 + tap] = fmaxf(fmaf(xv.y, sc1, sh1), 0.f);
                } else {
                    v[tap] = 0.f;
                    v[4 + tap] = 0.f;
                }
            }
            union { half8 v8; _Float16 e[8]; } uh, ul;
#pragma unroll
            for (int j = 0; j < 8; j++) splitf(v[j], uh.e[j], ul.e[j]);
            *(half8*)&AsH[wOff[u]] = uh.v8;
            *(half8*)&AsL[wOff[u]] = ul.v8;
        }
        // ---- stage B (pre-split weights, [o][k] rows) ----
#pragma unroll
        for (int u = 0; u < 2; u++) {
            const size_t go = (((size_t)(n0 + srow[u])) << 10) + kk0 + (skg << 3);
            *(half8*)&BsH[wOff[u]] = *(const half8*)(Whi + go);
            *(half8*)&BsL[wOff[u]] = *(const half8*)(Wlo + go);
        }
        __syncthreads();
        // ---- fragments + 48 MFMA ----
        half8 ah0 = *(const half8*)&AsH[haBase];
        half8 ah1 = *(const half8*)&AsH[haBase + 512];
        half8 al0 = *(const half8*)&AsL[haBase];
        half8 al1 = *(const half8*)&AsL[haBase + 512];
#pragma unroll
        for (int j = 0; j < 8; j++) {
            half8 bh = *(const half8*)&BsH[hbBase + j * 512];
            half8 bl = *(const half8*)&BsL[hbBase + j * 512];
            acc1[0][j] = MFMA16(ah0, bh, acc1[0][j]);
            acc2[0][j] = MFMA16(ah0, bl, acc2[0][j]);
            acc2[0][j] = MFMA16(al0, bh, acc2[0][j]);
            acc1[1][j] = MFMA16(ah1, bh, acc1[1][j]);
            acc2[1][j] = MFMA16(ah1, bl, acc2[1][j]);
            acc2[1][j] = MFMA16(al1, bh, acc2[1][j]);
        }
    }

    // ---- epilogue: C = acc1 + acc2/2048 + bias ----
    float bj[8];
#pragma unroll
    for (int j = 0; j < 8; j++) bj[j] = bias[n0 + j * 16 + fr];
#pragma unroll
    for (int i = 0; i < 2; i++)
#pragma unroll
        for (int q = 0; q < 4; q++) {
            const int m = m0 + wv * 32 + i * 16 + kgf * 4 + q;
            if (m < M) {
#pragma unroll
                for (int j = 0; j < 8; j++) {
                    float vv = acc1[i][j][q] + acc2[i][j][q] * 4.8828125e-4f + bj[j];
                    Y[((size_t)m << 8) + n0 + j * 16 + fr] = vv;
                }
            }
        }
}

// ---------------------------------------------------------------------------
// VQ argmin via split-fp16 MFMA: score = cnorm[k] - 2*dot(z, c_k).
// Same tile machinery; running row-min in registers across the 8 n0-tiles,
// final shfl_xor reduce over the 16 frag-cols with first-min tie-break.
// ---------------------------------------------------------------------------
__global__ __launch_bounds__(256)
void vq_argmin_mfma(const float* __restrict__ Z, const _Float16* __restrict__ Chi,
                    const _Float16* __restrict__ Clo, const float* __restrict__ cnorm,
                    int* __restrict__ ids)
{
    __shared__ _Float16 AsH[4096], AsL[4096], BsH[4096], BsL[4096];

    const int tid  = threadIdx.x;
    const int lane = tid & 63;
    const int wv   = tid >> 6;
    const int fr   = lane & 15;
    const int kgf  = lane >> 4;
    const int m0 = blockIdx.x * 128;

    const int haBase = wv * 1024 + ((fr * 32 + kgf * 8) ^ ((fr & 7) << 3));
    const int hbBase = (fr * 32 + kgf * 8) ^ ((fr & 7) << 3);

    const int skg = tid & 3;
    int srow[2];
    srow[0] = tid >> 2;
    srow[1] = 64 + (tid >> 2);
    int wOff[2];
#pragma unroll
    for (int u = 0; u < 2; u++) {
        int r = srow[u];
        wOff[u] = (r * 32 + skg * 8) ^ ((r & 7) << 3);
    }

    float bv[2][4];
    int   bk[2][4];
#pragma unroll
    for (int i = 0; i < 2; i++)
#pragma unroll
        for (int q = 0; q < 4; q++) { bv[i][q] = 3.4e38f; bk[i][q] = 0; }

    for (int n0t = 0; n0t < 1024; n0t += 128) {
        f32x4 acc1[2][8], acc2[2][8];
#pragma unroll
        for (int i = 0; i < 2; i++)
#pragma unroll
            for (int j = 0; j < 8; j++) {
                acc1[i][j] = (f32x4){0.f, 0.f, 0.f, 0.f};
                acc2[i][j] = (f32x4){0.f, 0.f, 0.f, 0.f};
            }

        for (int d0 = 0; d0 < 256; d0 += 32) {
            __syncthreads();
#pragma unroll
            for (int u = 0; u < 2; u++) {
                const float* zp = Z + (((size_t)(m0 + srow[u])) << 8) + d0 + (skg << 3);
                float4 z0 = *(const float4*)zp;
                float4 z1 = *(const float4*)(zp + 4);
                float v[8] = {z0.x, z0.y, z0.z, z0.w, z1.x, z1.y, z1.z, z1.w};
                union { half8 v8; _Float16 e[8]; } uh, ul;
#pragma unroll
                for (int j = 0; j < 8; j++) splitf(v[j], uh.e[j], ul.e[j]);
                *(half8*)&AsH[wOff[u]] = uh.v8;
                *(half8*)&AsL[wOff[u]] = ul.v8;
                const size_t go = (((size_t)(n0t + srow[u])) << 8) + d0 + (skg << 3);
                *(half8*)&BsH[wOff[u]] = *(const half8*)(Chi + go);
                *(half8*)&BsL[wOff[u]] = *(const half8*)(Clo + go);
            }
            __syncthreads();
            half8 ah0 = *(const half8*)&AsH[haBase];
            half8 ah1 = *(const half8*)&AsH[haBase + 512];
            half8 al0 = *(const half8*)&AsL[haBase];
            half8 al1 = *(const half8*)&AsL[haBase + 512];
#pragma unroll
            for (int j = 0; j < 8; j++) {
                half8 bh = *(const half8*)&BsH[hbBase + j * 512];
                half8 bl = *(const half8*)&BsL[hbBase + j * 512];
                acc1[0][j] = MFMA16(ah0, bh, acc1[0][j]);
                acc2[0][j] = MFMA16(ah0, bl, acc2[0][j]);
                acc2[0][j] = MFMA16(al0, bh, acc2[0][j]);
                acc1[1][j] = MFMA16(ah1, bh, acc1[1][j]);
                acc2[1][j] = MFMA16(ah1, bl, acc2[1][j]);
                acc2[1][j] = MFMA16(al1, bh, acc2[1][j]);
            }
        }
        // running min update for this 128-code tile
#pragma unroll
        for (int j = 0; j < 8; j++) {
            const int code = n0t + j * 16 + fr;
            const float cn = cnorm[code];
#pragma unroll
            for (int i = 0; i < 2; i++)
#pragma unroll
                for (int q = 0; q < 4; q++) {
                    float s = fmaf(-2.f, acc1[i][j][q] + acc2[i][j][q] * 4.8828125e-4f, cn);
                    if (s < bv[i][q] || (s == bv[i][q] && code < bk[i][q])) {
                        bv[i][q] = s; bk[i][q] = code;
                    }
                }
        }
    }

    // reduce across the 16 frag-cols (lanes differing in low 4 bits)
#pragma unroll
    for (int i = 0; i < 2; i++)
#pragma unroll
        for (int q = 0; q < 4; q++) {
            float v = bv[i][q];
            int   k = bk[i][q];
            for (int msk = 1; msk < 16; msk <<= 1) {
                float ov = __shfl_xor(v, msk, 64);
                int   ok = __shfl_xor(k, msk, 64);
                if (ov < v || (ov == v && ok < k)) { v = ov; k = ok; }
            }
            if (fr == 0) ids[m0 + wv * 32 + i * 16 + kgf * 4 + q] = k;
        }
}

// ---------------------------------------------------------------------------
// Counting sort for segment sums (int atomics; fully parallel).
// ---------------------------------------------------------------------------
__global__ __launch_bounds__(256)
void vq_hist(const int* __restrict__ ids, unsigned* __restrict__ cnt)
{
    int m = blockIdx.x * 256 + threadIdx.x;
    atomicAdd(&cnt[ids[m]], 1u);
}

__global__ __launch_bounds__(1024)
void vq_scan(const unsigned* __restrict__ cnt, int* __restrict__ offs, int* __restrict__ curs)
{
    __shared__ int sm[1024];
    const int k = threadIdx.x;
    const int c = (int)cnt[k];
    sm[k] = c;
    __syncthreads();
    for (int off = 1; off < 1024; off <<= 1) {
        int v = (k >= off) ? sm[k - off] : 0;
        __syncthreads();
        sm[k] += v;
        __syncthreads();
    }
    int exc = sm[k] - c;
    offs[k] = exc;
    curs[k] = exc;
    if (k == 1023) offs[1024] = sm[k];
}

__global__ __launch_bounds__(256)
void vq_scatter(const int* __restrict__ ids, int* __restrict__ curs,
                int* __restrict__ perm, int* __restrict__ scode)
{
    int m = blockIdx.x * 256 + threadIdx.x;
    int id = ids[m];
    int pos = atomicAdd(&curs[id], 1);
    perm[pos] = m;
    scode[pos] = id;
}

// ---------------------------------------------------------------------------
// z_q gather: fully parallel, float4/lane. 4 rows per block (64 lanes/row).
// ---------------------------------------------------------------------------
__global__ __launch_bounds__(256)
void vq_gather_zq(const int* __restrict__ ids, const float* __restrict__ cb,
                  float* __restrict__ zq)
{
    const int row = blockIdx.x * 4 + (threadIdx.x >> 6);
    const int d4  = (threadIdx.x & 63) << 2;
    const int id  = ids[row];
    *(float4*)(zq + ((size_t)row << 8) + d4) =
        *(const float4*)(cb + ((size_t)id << 8) + d4);
}

// ---------------------------------------------------------------------------
// Segment sum over sorted perm: 256 positions per block, thread = dim.
// ---------------------------------------------------------------------------
__global__ __launch_bounds__(256)
void vq_segsum(const int* __restrict__ perm, const int* __restrict__ scode,
               const float* __restrict__ Z, float* __restrict__ sums)
{
    __shared__ int pm[256];
    __shared__ int cd[256];
    const int p0 = blockIdx.x * 256;
    const int d  = threadIdx.x;
    pm[d] = perm[p0 + d];
    cd[d] = scode[p0 + d];
    __syncthreads();
    float s = 0.f;
    int cur = cd[0];
    for (int i = 0; i < 256; i++) {
        int c = cd[i];                          // wave-uniform
        float v = Z[((size_t)pm[i] << 8) + d];  // coalesced 1KB row
        if (c != cur) {
            atomicAdd(&sums[((size_t)cur << 8) + d], s);
            s = 0.f;
            cur = c;
        }
        s += v;
    }
    atomicAdd(&sums[((size_t)cur << 8) + d], s);
}

__global__ __launch_bounds__(1024)
void vq_fin1(const unsigned* __restrict__ cnt, const float* __restrict__ ema_cs,
             float* __restrict__ ecs, float* __restrict__ nval)
{
    __shared__ float sm[1024];
    const int k = threadIdx.x;
    float e = fmaf(ema_cs[k], 0.99f, 0.01f * (float)cnt[k]);
    ecs[k] = e;
    sm[k] = e;
    __syncthreads();
    for (int off = 512; off > 0; off >>= 1) {
        if (k < off) sm[k] += sm[k + off];
        __syncthreads();
    }
    if (k == 0) nval[0] = sm[0];
}

__global__ __launch_bounds__(256)
void vq_fin2(const float* __restrict__ ema_w, const float* __restrict__ sums,
             const float* __restrict__ ecs, const float* __restrict__ nval,
             float* __restrict__ cbout)
{
    const int k = blockIdx.x, d = threadIdx.x;
    const float n = nval[0];
    const float sm = ((ecs[k] + 1e-5f) / (n + 0.01024f)) * n;  // (e+eps)/(n+K*eps)*n
    const size_t idx = ((size_t)k << 8) + d;
    cbout[idx] = fmaf(ema_w[idx], 0.99f, 0.01f * sums[idx]) / sm;
}

// ===========================================================================
extern "C" void kernel_launch(void* const* d_in, const int* in_sizes, int n_in,
                              void* d_out, int out_size, void* d_ws, size_t ws_size,
                              hipStream_t stream)
{
    (void)in_sizes; (void)n_in; (void)out_size; (void)ws_size;

    const float* x = (const float*)d_in[0];
    const float* w[7]; const float* bias[7];
    for (int i = 1; i <= 6; i++) {
        w[i]    = (const float*)d_in[1 + 2 * (i - 1)];
        bias[i] = (const float*)d_in[2 + 2 * (i - 1)];
    }
    const float* g[6]; const float* be[6];
    for (int i = 1; i <= 5; i++) {
        g[i]  = (const float*)d_in[13 + 2 * (i - 1)];
        be[i] = (const float*)d_in[14 + 2 * (i - 1)];
    }
    const float* codebook = (const float*)d_in[23];
    const float* ema_w    = (const float*)d_in[24];
    const float* ema_cs   = (const float*)d_in[25];

    float* out   = (float*)d_out;
    float* z_e   = out;                      // 32*4096*256
    float* z_q   = out + 33554432;           // 32*4096*256
    float* cbout = out + 67108864;           // 1024*256
    float* ecs   = out + 67371008;           // 1024

    // workspace layout (floats)
    float* ws    = (float*)d_ws;
    float* bufA  = ws;                            // 32*4097*256 = 33,570,816
    float* bufB  = z_q;                           // exact fit for T=4096 layers
    _Float16* wthi = (_Float16*)(ws + 33570816);  // 5*262144 halves (655,360 fl)
    _Float16* wtlo = (_Float16*)(ws + 34226176);  // 5*262144 halves
    _Float16* cbhi = (_Float16*)(ws + 34881536);  // 262144 halves (131,072 fl)
    _Float16* cblo = (_Float16*)(ws + 35012608);  // 262144 halves
    float* cnorm = ws + 35143680;                 // 1024
    float* scsh  = cnorm + 1024;                  // 5 * 512
    float* part  = scsh + 2560;                   // 2 * 65536 (dead at VQ time)
    float* sums  = part + 131072;                 // 262144
    float* nval  = sums + 262144;                 // 16
    int*      ids  = (int*)(nval + 16);           // 131072
    unsigned* cnt  = (unsigned*)(ids + 131072);   // 1024
    int*      offs = (int*)(cnt + 1024);          // 1025
    int*      curs = offs + 1025;                 // 1024
    int*      perm = curs + 1024;                 // 131072
    int*      scode = (int*)part;                 // reuse BN partial region

    hipMemsetAsync(cnt, 0, 1024 * sizeof(unsigned), stream);
    hipMemsetAsync(sums, 0, 262144 * sizeof(float), stream);

    // prep: split weights (native [o][i][k] layout == [o][ci*4+tap]) + codebook
    for (int i = 0; i < 5; i++)
        prep_split<<<1024, 256, 0, stream>>>(w[i + 2], wthi + (size_t)i * 262144,
                                             wtlo + (size_t)i * 262144);
    prep_split<<<1024, 256, 0, stream>>>(codebook, cbhi, cblo);
    prep_cnorm<<<1024, 256, 0, stream>>>(codebook, cnorm);

    // layer 1: x -> bufA (T 4096 -> 4097, pad 2)
    conv1_kernel<<<dim3(129, 32), 256, 0, stream>>>(x, w[1], bias[1], bufA);
    bn_partial<<<256, 256, 0, stream>>>(bufA, 32 * 4097, part);
    bn_finalize<<<1, 256, 0, stream>>>(part, g[1], be[1], 1.f / 131104.f, scsh + 0);

    // layer 2
    conv_gemm_mfma<4097, 4096, 1><<<dim3(2, 1024), 256, 0, stream>>>(
        bufA, scsh + 0, wthi, wtlo, bias[2], bufB);
    bn_partial<<<256, 256, 0, stream>>>(bufB, 32 * 4096, part);
    bn_finalize<<<1, 256, 0, stream>>>(part, g[2], be[2], 1.f / 131072.f, scsh + 512);

    // layer 3
    conv_gemm_mfma<4096, 4097, 2><<<dim3(2, 1025), 256, 0, stream>>>(
        bufB, scsh + 512, wthi + 262144, wtlo + 262144, bias[3], bufA);
    bn_partial<<<256, 256, 0, stream>>>(bufA, 32 * 4097, part);
    bn_finalize<<<1, 256, 0, stream>>>(part, g[3], be[3], 1.f / 131104.f, scsh + 1024);

    // layer 4
    conv_gemm_mfma<4097, 4096, 1><<<dim3(2, 1024), 256, 0, stream>>>(
        bufA, scsh + 1024, wthi + 524288, wtlo + 524288, bias[4], bufB);
    bn_partial<<<256, 256, 0, stream>>>(bufB, 32 * 4096, part);
    bn_finalize<<<1, 256, 0, stream>>>(part, g[4], be[4], 1.f / 131072.f, scsh + 1536);

    // layer 5
    conv_gemm_mfma<4096, 4097, 2><<<dim3(2, 1025), 256, 0, stream>>>(
        bufB, scsh + 1536, wthi + 786432, wtlo + 786432, bias[5], bufA);
    bn_partial<<<256, 256, 0, stream>>>(bufA, 32 * 4097, part);
    bn_finalize<<<1, 256, 0, stream>>>(part, g[5], be[5], 1.f / 131104.f, scsh + 2048);

    // layer 6: -> z_e (no BN/relu on output)
    conv_gemm_mfma<4097, 4096, 1><<<dim3(2, 1024), 256, 0, stream>>>(
        bufA, scsh + 2048, wthi + 1048576, wtlo + 1048576, bias[6], z_e);

    // VQ
    vq_argmin_mfma<<<1024, 256, 0, stream>>>(z_e, cbhi, cblo, cnorm, ids);
    vq_hist<<<512, 256, 0, stream>>>(ids, cnt);
    vq_scan<<<1, 1024, 0, stream>>>(cnt, offs, curs);
    vq_scatter<<<512, 256, 0, stream>>>(ids, curs, perm, scode);
    vq_gather_zq<<<32768, 256, 0, stream>>>(ids, codebook, z_q);
    vq_segsum<<<512, 256, 0, stream>>>(perm, scode, z_e, sums);
    vq_fin1<<<1, 1024, 0, stream>>>(cnt, ema_cs, ecs, nval);
    vq_fin2<<<1024, 256, 0, stream>>>(ema_w, sums, ecs, nval, cbout);
}

// Round 3
// 4357.743 us; speedup vs baseline: 1.6886x; 1.5817x over previous
//
#include <hip/hip_runtime.h>
#include <cstdint>
#include <cstddef>

// ===========================================================================
// VQ-VAE encoder: 6x conv1d(k=4) + BN(train) + relu chain, then VQ (argmin,
// EMA codebook update). B=32, T=4096, D=256, K=1024.
//
// R4b: R4 with compile fix (vector-element reference binding in splitf calls).
//  - all inter-layer activations stored as pre-split fp16 (hi, lo*2048)
//    pairs; BN+relu+re-split applied once per layer in-place (bn_split_h),
//    so the GEMM A-stage is a pure 16B copy (no BN/splitf VALU in the loop).
//  - register-prefetch pipeline: step s+1's global loads issue right after
//    the first barrier and complete under step s's MFMA phase.
//  - K order = tap*256+ci: A-stage reads one contiguous 64B row slice.
// Split numerics: a = hi + lo/2048 (fp16 halves); C = Ahi*Bhi + (Ahi*Blo' +
// Alo'*Bhi)/2048. hi*hi products are exact in fp32; dropped lo*lo ~ 2^-22.
// ===========================================================================

typedef _Float16 half8 __attribute__((ext_vector_type(8)));
typedef float f32x4 __attribute__((ext_vector_type(4)));

#define MFMA16(a, b, c) __builtin_amdgcn_mfma_f32_16x16x32_f16((a), (b), (c), 0, 0, 0)
#define INV2048 4.8828125e-4f

__device__ __forceinline__ void splitf(float v, _Float16& h, _Float16& l)
{
    _Float16 hh = (_Float16)v;
    h = hh;
    l = (_Float16)((v - (float)hh) * 2048.0f);
}
__device__ __forceinline__ float joinf(_Float16 h, _Float16 l)
{
    return (float)h + (float)l * INV2048;
}

// ---------------------------------------------------------------------------
// conv1: x (32,4096,12) -> Y halves (32,4097,256), pad=2, k=4.
// ---------------------------------------------------------------------------
__global__ __launch_bounds__(256)
void conv1_kernel(const float* __restrict__ x, const float* __restrict__ w1,
                  const float* __restrict__ b1, _Float16* __restrict__ YH,
                  _Float16* __restrict__ YL)
{
    const int b  = blockIdx.y;
    const int t0 = blockIdx.x * 32;
    const int oc = threadIdx.x;
    __shared__ float xl[35 * 12];
    for (int idx = threadIdx.x; idx < 420; idx += 256) {
        int tt = t0 - 2 + idx / 12;
        int i  = idx % 12;
        xl[idx] = (tt >= 0 && tt < 4096) ? x[((size_t)b * 4096 + tt) * 12 + i] : 0.f;
    }
    float w[48];
#pragma unroll
    for (int q = 0; q < 12; q++)
        *(float4*)&w[q * 4] = *(const float4*)(w1 + (size_t)oc * 48 + q * 4);
    __syncthreads();
    const float bias = b1[oc];
    for (int dt = 0; dt < 32; dt++) {
        int t = t0 + dt;
        if (t >= 4097) break;
        float a = bias;
#pragma unroll
        for (int i = 0; i < 12; i++)
#pragma unroll
            for (int k = 0; k < 4; k++)
                a = fmaf(xl[(dt + k) * 12 + i], w[i * 4 + k], a);
        _Float16 h, l;
        splitf(a, h, l);
        const size_t o = ((size_t)b * 4097 + t) * 256 + oc;
        YH[o] = h;
        YL[o] = l;
    }
}

// ---------------------------------------------------------------------------
// Deterministic BN stats over split-half tensors.
// ---------------------------------------------------------------------------
__global__ __launch_bounds__(256)
void bn_partial_h(const _Float16* __restrict__ YH, const _Float16* __restrict__ YL,
                  int M, float* __restrict__ part)
{
    const int j = blockIdx.x;   // 0..255
    const int c = threadIdx.x;  // channel
    const int chunk = (M + 255) / 256;
    int r0 = j * chunk;
    int r1 = r0 + chunk; if (r1 > M) r1 = M;
    float s = 0.f, s2 = 0.f;
    for (int r = r0; r < r1; r++) {
        const size_t o = ((size_t)r << 8) + c;
        float v = joinf(YH[o], YL[o]);
        s += v;
        s2 = fmaf(v, v, s2);
    }
    part[j * 256 + c]         = s;
    part[65536 + j * 256 + c] = s2;
}

__global__ __launch_bounds__(256)
void bn_finalize(const float* __restrict__ part, const float* __restrict__ g,
                 const float* __restrict__ be, float invM, float* __restrict__ scsh)
{
    const int c = threadIdx.x;
    float s = 0.f, s2 = 0.f;
    for (int j = 0; j < 256; j++) {
        s  += part[j * 256 + c];
        s2 += part[65536 + j * 256 + c];
    }
    float mean = s * invM;
    float var  = fmaf(s2, invM, -mean * mean);
    float sc   = g[c] * rsqrtf(var + 1e-5f);
    scsh[c]       = sc;
    scsh[256 + c] = fmaf(-mean, sc, be[c]);
}

// ---------------------------------------------------------------------------
// In-place BN+relu+re-split on a split-half tensor. N8 = numel/8.
// ---------------------------------------------------------------------------
__global__ __launch_bounds__(256)
void bn_split_h(_Float16* __restrict__ YH, _Float16* __restrict__ YL,
                const float* __restrict__ scsh, int N8)
{
    int idx = blockIdx.x * 256 + threadIdx.x;
    const int stride = gridDim.x * 256;
    for (; idx < N8; idx += stride) {
        const size_t e0 = (size_t)idx * 8;
        const int ci0 = (int)(e0 & 255);
        half8 h = *(half8*)(YH + e0);
        half8 l = *(half8*)(YL + e0);
        float4 scA = *(const float4*)(scsh + ci0);
        float4 scB = *(const float4*)(scsh + ci0 + 4);
        float4 shA = *(const float4*)(scsh + 256 + ci0);
        float4 shB = *(const float4*)(scsh + 256 + ci0 + 4);
        float sc[8] = {scA.x, scA.y, scA.z, scA.w, scB.x, scB.y, scB.z, scB.w};
        float sh[8] = {shA.x, shA.y, shA.z, shA.w, shB.x, shB.y, shB.z, shB.w};
#pragma unroll
        for (int e = 0; e < 8; e++) {
            float v = joinf(h[e], l[e]);
            v = fmaxf(fmaf(v, sc[e], sh[e]), 0.f);
            _Float16 hh, ll;
            splitf(v, hh, ll);
            h[e] = hh;
            l[e] = ll;
        }
        *(half8*)(YH + e0) = h;
        *(half8*)(YL + e0) = l;
    }
}

// ---------------------------------------------------------------------------
// Plain fp32 -> split halves (z_e, codebook). N8 = numel/8.
// ---------------------------------------------------------------------------
__global__ __launch_bounds__(256)
void split8(const float* __restrict__ Z, _Float16* __restrict__ ZH,
            _Float16* __restrict__ ZL, int N8)
{
    int idx = blockIdx.x * 256 + threadIdx.x;
    const int stride = gridDim.x * 256;
    for (; idx < N8; idx += stride) {
        const size_t e0 = (size_t)idx * 8;
        float4 a = *(const float4*)(Z + e0);
        float4 b = *(const float4*)(Z + e0 + 4);
        float v[8] = {a.x, a.y, a.z, a.w, b.x, b.y, b.z, b.w};
        half8 h, l;
#pragma unroll
        for (int e = 0; e < 8; e++) {
            _Float16 hh, ll;
            splitf(v[e], hh, ll);
            h[e] = hh;
            l[e] = ll;
        }
        *(half8*)(ZH + e0) = h;
        *(half8*)(ZL + e0) = l;
    }
}

// w (256,256,4) [o][ci][tap] -> split halves at [o][tap*256+ci]
__global__ __launch_bounds__(256)
void prep_w_split(const float* __restrict__ w, _Float16* __restrict__ hi,
                  _Float16* __restrict__ lo)
{
    int idx = blockIdx.x * 256 + threadIdx.x;  // 262144
    int o   = idx >> 10, rem = idx & 1023;
    int tap = rem >> 8,  ci  = rem & 255;
    float v = w[((size_t)o << 10) + (ci << 2) + tap];
    _Float16 h, l;
    splitf(v, h, l);
    hi[idx] = h;
    lo[idx] = l;
}

// per-code squared norms (fp32 exact)
__global__ __launch_bounds__(256)
void prep_cnorm(const float* __restrict__ cb, float* __restrict__ cnorm)
{
    const int k = blockIdx.x;   // 1024
    const int d = threadIdx.x;  // 256
    float v = cb[((size_t)k << 8) + d];
    __shared__ float sm[256];
    sm[d] = v * v;
    __syncthreads();
    for (int off = 128; off > 0; off >>= 1) {
        if (d < off) sm[d] += sm[d + off];
        __syncthreads();
    }
    if (d == 0) cnorm[k] = sm[0];
}

// ---------------------------------------------------------------------------
// conv2..6 as split-fp16 MFMA GEMM, 128x128 tile, BK=32, register-prefetch
// pipeline. K index: k = tap*256 + ci (A-stage = contiguous 64B row slice,
// matches the prep_w_split weight layout). LDS [row][32 halves] with
// half_idx ^= (row&7)<<3 swizzle (unchanged, verified machinery).
// ---------------------------------------------------------------------------
template<int T_IN, int T_OUT, int PAD, bool F32OUT>
__global__ __launch_bounds__(256)
void conv_gemm_mfma(const _Float16* __restrict__ XH, const _Float16* __restrict__ XL,
                    const _Float16* __restrict__ WH, const _Float16* __restrict__ WL,
                    const float* __restrict__ bias, float* __restrict__ Yf,
                    _Float16* __restrict__ YH, _Float16* __restrict__ YL)
{
    constexpr int M = 32 * T_OUT;
    __shared__ _Float16 AsH[4096], AsL[4096], BsH[4096], BsL[4096];

    const int tid  = threadIdx.x;
    const int lane = tid & 63;
    const int wv   = tid >> 6;     // wave 0..3 -> rows 32*wv..32*wv+31
    const int fr   = lane & 15;
    const int kgf  = lane >> 4;
    const int m0 = blockIdx.y * 128;
    const int n0 = blockIdx.x * 128;

    const int haBase = wv * 1024 + ((fr * 32 + kgf * 8) ^ ((fr & 7) << 3));
    const int hbBase = (fr * 32 + kgf * 8) ^ ((fr & 7) << 3);

    // staging tasks: u in {0,1}: row = (tid>>2)+64u, 16B granule skg = tid&3
    const int skg = tid & 3;
    int wOff[2], tOut[2];
    long long aBase[2];
    size_t bBase[2];
    bool mok[2];
#pragma unroll
    for (int u = 0; u < 2; u++) {
        int r = (tid >> 2) + 64 * u;
        wOff[u] = (r * 32 + skg * 8) ^ ((r & 7) << 3);
        int m = m0 + r;
        mok[u] = (m < M);
        int b;
        if (T_OUT == 4096) b = m >> 12;
        else               b = (m - (m >> 12)) >> 12;   // m/4097
        int t = m - b * T_OUT;
        tOut[u]  = t;
        aBase[u] = (((long long)b * T_IN + t) << 8) + (skg << 3);
        bBase[u] = (((size_t)(n0 + r)) << 10) + (skg << 3);
    }

    half8 rAH[2], rAL[2], rBH[2], rBL[2];
    const half8 hz = {(_Float16)0, (_Float16)0, (_Float16)0, (_Float16)0,
                      (_Float16)0, (_Float16)0, (_Float16)0, (_Float16)0};

    auto LOAD = [&](int s) {
        const int tap = s >> 3;
        const int ci0 = (s & 7) << 5;
        const int dt  = tap - PAD;
#pragma unroll
        for (int u = 0; u < 2; u++) {
            const int ti = tOut[u] + dt;
            if (mok[u] && ti >= 0 && ti < T_IN) {
                const long long ga = aBase[u] + ((long long)dt << 8) + ci0;
                rAH[u] = *(const half8*)(XH + ga);
                rAL[u] = *(const half8*)(XL + ga);
            } else {
                rAH[u] = hz;
                rAL[u] = hz;
            }
            const size_t gb = bBase[u] + ((size_t)s << 5);
            rBH[u] = *(const half8*)(WH + gb);
            rBL[u] = *(const half8*)(WL + gb);
        }
    };

    f32x4 acc1[2][8], acc2[2][8];
#pragma unroll
    for (int i = 0; i < 2; i++)
#pragma unroll
        for (int j = 0; j < 8; j++) {
            acc1[i][j] = (f32x4){0.f, 0.f, 0.f, 0.f};
            acc2[i][j] = (f32x4){0.f, 0.f, 0.f, 0.f};
        }

    LOAD(0);
    for (int s = 0; s < 32; s++) {
        *(half8*)&AsH[wOff[0]] = rAH[0];
        *(half8*)&AsH[wOff[1]] = rAH[1];
        *(half8*)&AsL[wOff[0]] = rAL[0];
        *(half8*)&AsL[wOff[1]] = rAL[1];
        *(half8*)&BsH[wOff[0]] = rBH[0];
        *(half8*)&BsH[wOff[1]] = rBH[1];
        *(half8*)&BsL[wOff[0]] = rBL[0];
        *(half8*)&BsL[wOff[1]] = rBL[1];
        __syncthreads();
        if (s + 1 < 32) LOAD(s + 1);   // prefetch under the MFMA phase
        half8 ah0 = *(const half8*)&AsH[haBase];
        half8 ah1 = *(const half8*)&AsH[haBase + 512];
        half8 al0 = *(const half8*)&AsL[haBase];
        half8 al1 = *(const half8*)&AsL[haBase + 512];
#pragma unroll
        for (int j = 0; j < 8; j++) {
            half8 bh = *(const half8*)&BsH[hbBase + j * 512];
            half8 bl = *(const half8*)&BsL[hbBase + j * 512];
            acc1[0][j] = MFMA16(ah0, bh, acc1[0][j]);
            acc2[0][j] = MFMA16(ah0, bl, acc2[0][j]);
            acc2[0][j] = MFMA16(al0, bh, acc2[0][j]);
            acc1[1][j] = MFMA16(ah1, bh, acc1[1][j]);
            acc2[1][j] = MFMA16(ah1, bl, acc2[1][j]);
            acc2[1][j] = MFMA16(al1, bh, acc2[1][j]);
        }
        __syncthreads();
    }

    // ---- epilogue: C = acc1 + acc2/2048 + bias ----
    float bj[8];
#pragma unroll
    for (int j = 0; j < 8; j++) bj[j] = bias[n0 + j * 16 + fr];
#pragma unroll
    for (int i = 0; i < 2; i++)
#pragma unroll
        for (int q = 0; q < 4; q++) {
            const int m = m0 + wv * 32 + i * 16 + kgf * 4 + q;
            if (m < M) {
#pragma unroll
                for (int j = 0; j < 8; j++) {
                    float vv = acc1[i][j][q] + acc2[i][j][q] * INV2048 + bj[j];
                    const size_t o = ((size_t)m << 8) + n0 + j * 16 + fr;
                    if constexpr (F32OUT) {
                        Yf[o] = vv;
                    } else {
                        _Float16 h, l;
                        splitf(vv, h, l);
                        YH[o] = h;
                        YL[o] = l;
                    }
                }
            }
        }
}

// ---------------------------------------------------------------------------
// VQ argmin via split-fp16 MFMA with the same prefetch pipeline.
// Flat steps ss=0..63: code tile nt=ss>>3 (128 codes), d-step (ss&7)*32.
// score = cnorm[k] - 2*dot(z, c_k); running min + shfl reduce.
// ---------------------------------------------------------------------------
__global__ __launch_bounds__(256)
void vq_argmin_mfma(const _Float16* __restrict__ ZH, const _Float16* __restrict__ ZL,
                    const _Float16* __restrict__ CH, const _Float16* __restrict__ CL,
                    const float* __restrict__ cnorm, int* __restrict__ ids)
{
    __shared__ _Float16 AsH[4096], AsL[4096], BsH[4096], BsL[4096];

    const int tid  = threadIdx.x;
    const int lane = tid & 63;
    const int wv   = tid >> 6;
    const int fr   = lane & 15;
    const int kgf  = lane >> 4;
    const int m0 = blockIdx.x * 128;

    const int haBase = wv * 1024 + ((fr * 32 + kgf * 8) ^ ((fr & 7) << 3));
    const int hbBase = (fr * 32 + kgf * 8) ^ ((fr & 7) << 3);

    const int skg = tid & 3;
    int wOff[2];
    size_t aBase[2], bBase[2];
#pragma unroll
    for (int u = 0; u < 2; u++) {
        int r = (tid >> 2) + 64 * u;
        wOff[u]  = (r * 32 + skg * 8) ^ ((r & 7) << 3);
        aBase[u] = (((size_t)(m0 + r)) << 8) + (skg << 3);
        bBase[u] = (((size_t)r) << 8) + (skg << 3);
    }

    half8 rAH[2], rAL[2], rBH[2], rBL[2];

    auto LOADV = [&](int ss) {
        const int nt = ss >> 3;
        const int dd = (ss & 7) << 5;
#pragma unroll
        for (int u = 0; u < 2; u++) {
            const size_t ga = aBase[u] + dd;
            rAH[u] = *(const half8*)(ZH + ga);
            rAL[u] = *(const half8*)(ZL + ga);
            const size_t gb = bBase[u] + ((size_t)nt << 15) + dd;
            rBH[u] = *(const half8*)(CH + gb);
            rBL[u] = *(const half8*)(CL + gb);
        }
    };

    float bv[2][4];
    int   bk[2][4];
#pragma unroll
    for (int i = 0; i < 2; i++)
#pragma unroll
        for (int q = 0; q < 4; q++) { bv[i][q] = 3.4e38f; bk[i][q] = 0; }

    f32x4 acc1[2][8], acc2[2][8];

    LOADV(0);
    for (int nt = 0; nt < 8; nt++) {
#pragma unroll
        for (int i = 0; i < 2; i++)
#pragma unroll
            for (int j = 0; j < 8; j++) {
                acc1[i][j] = (f32x4){0.f, 0.f, 0.f, 0.f};
                acc2[i][j] = (f32x4){0.f, 0.f, 0.f, 0.f};
            }
        for (int dstep = 0; dstep < 8; dstep++) {
            const int ss = nt * 8 + dstep;
            *(half8*)&AsH[wOff[0]] = rAH[0];
            *(half8*)&AsH[wOff[1]] = rAH[1];
            *(half8*)&AsL[wOff[0]] = rAL[0];
            *(half8*)&AsL[wOff[1]] = rAL[1];
            *(half8*)&BsH[wOff[0]] = rBH[0];
            *(half8*)&BsH[wOff[1]] = rBH[1];
            *(half8*)&BsL[wOff[0]] = rBL[0];
            *(half8*)&BsL[wOff[1]] = rBL[1];
            __syncthreads();
            if (ss + 1 < 64) LOADV(ss + 1);
            half8 ah0 = *(const half8*)&AsH[haBase];
            half8 ah1 = *(const half8*)&AsH[haBase + 512];
            half8 al0 = *(const half8*)&AsL[haBase];
            half8 al1 = *(const half8*)&AsL[haBase + 512];
#pragma unroll
            for (int j = 0; j < 8; j++) {
                half8 bh = *(const half8*)&BsH[hbBase + j * 512];
                half8 bl = *(const half8*)&BsL[hbBase + j * 512];
                acc1[0][j] = MFMA16(ah0, bh, acc1[0][j]);
                acc2[0][j] = MFMA16(ah0, bl, acc2[0][j]);
                acc2[0][j] = MFMA16(al0, bh, acc2[0][j]);
                acc1[1][j] = MFMA16(ah1, bh, acc1[1][j]);
                acc2[1][j] = MFMA16(ah1, bl, acc2[1][j]);
                acc2[1][j] = MFMA16(al1, bh, acc2[1][j]);
            }
            __syncthreads();
        }
        // running min update for this 128-code tile
        const int n0t = nt * 128;
#pragma unroll
        for (int j = 0; j < 8; j++) {
            const int code = n0t + j * 16 + fr;
            const float cn = cnorm[code];
#pragma unroll
            for (int i = 0; i < 2; i++)
#pragma unroll
                for (int q = 0; q < 4; q++) {
                    float s = fmaf(-2.f, acc1[i][j][q] + acc2[i][j][q] * INV2048, cn);
                    if (s < bv[i][q] || (s == bv[i][q] && code < bk[i][q])) {
                        bv[i][q] = s; bk[i][q] = code;
                    }
                }
        }
    }

    // reduce across the 16 frag-cols
#pragma unroll
    for (int i = 0; i < 2; i++)
#pragma unroll
        for (int q = 0; q < 4; q++) {
            float v = bv[i][q];
            int   k = bk[i][q];
            for (int msk = 1; msk < 16; msk <<= 1) {
                float ov = __shfl_xor(v, msk, 64);
                int   ok = __shfl_xor(k, msk, 64);
                if (ov < v || (ov == v && ok < k)) { v = ov; k = ok; }
            }
            if (fr == 0) ids[m0 + wv * 32 + i * 16 + kgf * 4 + q] = k;
        }
}

// ---------------------------------------------------------------------------
// Counting sort for segment sums (int atomics; fully parallel).
// ---------------------------------------------------------------------------
__global__ __launch_bounds__(256)
void vq_hist(const int* __restrict__ ids, unsigned* __restrict__ cnt)
{
    int m = blockIdx.x * 256 + threadIdx.x;
    atomicAdd(&cnt[ids[m]], 1u);
}

__global__ __launch_bounds__(1024)
void vq_scan(const unsigned* __restrict__ cnt, int* __restrict__ offs, int* __restrict__ curs)
{
    __shared__ int sm[1024];
    const int k = threadIdx.x;
    const int c = (int)cnt[k];
    sm[k] = c;
    __syncthreads();
    for (int off = 1; off < 1024; off <<= 1) {
        int v = (k >= off) ? sm[k - off] : 0;
        __syncthreads();
        sm[k] += v;
        __syncthreads();
    }
    int exc = sm[k] - c;
    offs[k] = exc;
    curs[k] = exc;
    if (k == 1023) offs[1024] = sm[k];
}

__global__ __launch_bounds__(256)
void vq_scatter(const int* __restrict__ ids, int* __restrict__ curs,
                int* __restrict__ perm, int* __restrict__ scode)
{
    int m = blockIdx.x * 256 + threadIdx.x;
    int id = ids[m];
    int pos = atomicAdd(&curs[id], 1);
    perm[pos] = m;
    scode[pos] = id;
}

__global__ __launch_bounds__(256)
void vq_gather_zq(const int* __restrict__ ids, const float* __restrict__ cb,
                  float* __restrict__ zq)
{
    const int row = blockIdx.x * 4 + (threadIdx.x >> 6);
    const int d4  = (threadIdx.x & 63) << 2;
    const int id  = ids[row];
    *(float4*)(zq + ((size_t)row << 8) + d4) =
        *(const float4*)(cb + ((size_t)id << 8) + d4);
}

__global__ __launch_bounds__(256)
void vq_segsum(const int* __restrict__ perm, const int* __restrict__ scode,
               const float* __restrict__ Z, float* __restrict__ sums)
{
    __shared__ int pm[256];
    __shared__ int cd[256];
    const int p0 = blockIdx.x * 256;
    const int d  = threadIdx.x;
    pm[d] = perm[p0 + d];
    cd[d] = scode[p0 + d];
    __syncthreads();
    float s = 0.f;
    int cur = cd[0];
    for (int i = 0; i < 256; i++) {
        int c = cd[i];
        float v = Z[((size_t)pm[i] << 8) + d];
        if (c != cur) {
            atomicAdd(&sums[((size_t)cur << 8) + d], s);
            s = 0.f;
            cur = c;
        }
        s += v;
    }
    atomicAdd(&sums[((size_t)cur << 8) + d], s);
}

__global__ __launch_bounds__(1024)
void vq_fin1(const unsigned* __restrict__ cnt, const float* __restrict__ ema_cs,
             float* __restrict__ ecs, float* __restrict__ nval)
{
    __shared__ float sm[1024];
    const int k = threadIdx.x;
    float e = fmaf(ema_cs[k], 0.99f, 0.01f * (float)cnt[k]);
    ecs[k] = e;
    sm[k] = e;
    __syncthreads();
    for (int off = 512; off > 0; off >>= 1) {
        if (k < off) sm[k] += sm[k + off];
        __syncthreads();
    }
    if (k == 0) nval[0] = sm[0];
}

__global__ __launch_bounds__(256)
void vq_fin2(const float* __restrict__ ema_w, const float* __restrict__ sums,
             const float* __restrict__ ecs, const float* __restrict__ nval,
             float* __restrict__ cbout)
{
    const int k = blockIdx.x, d = threadIdx.x;
    const float n = nval[0];
    const float sm = ((ecs[k] + 1e-5f) / (n + 0.01024f)) * n;
    const size_t idx = ((size_t)k << 8) + d;
    cbout[idx] = fmaf(ema_w[idx], 0.99f, 0.01f * sums[idx]) / sm;
}

// ===========================================================================
extern "C" void kernel_launch(void* const* d_in, const int* in_sizes, int n_in,
                              void* d_out, int out_size, void* d_ws, size_t ws_size,
                              hipStream_t stream)
{
    (void)in_sizes; (void)n_in; (void)out_size; (void)ws_size;

    const float* x = (const float*)d_in[0];
    const float* w[7]; const float* bias[7];
    for (int i = 1; i <= 6; i++) {
        w[i]    = (const float*)d_in[1 + 2 * (i - 1)];
        bias[i] = (const float*)d_in[2 + 2 * (i - 1)];
    }
    const float* g[6]; const float* be[6];
    for (int i = 1; i <= 5; i++) {
        g[i]  = (const float*)d_in[13 + 2 * (i - 1)];
        be[i] = (const float*)d_in[14 + 2 * (i - 1)];
    }
    const float* codebook = (const float*)d_in[23];
    const float* ema_w    = (const float*)d_in[24];
    const float* ema_cs   = (const float*)d_in[25];

    float* out   = (float*)d_out;
    float* z_e   = out;                      // 32*4096*256
    float* z_q   = out + 33554432;           // 32*4096*256
    float* cbout = out + 67108864;           // 1024*256
    float* ecs   = out + 67371008;           // 1024

    // ping pair (4097-sized layers) in ws; pong pair (4096-sized) in z_q region
    float* ws = (float*)d_ws;
    _Float16* pingH = (_Float16*)ws;             // 131104*256 = 33,562,624 halves
    _Float16* pingL = pingH + 33562624;
    _Float16* pongH = (_Float16*)z_q;            // 131072*256 halves (exact fit)
    _Float16* pongL = pongH + 33554432;

    float* wsf   = ws + 33562624;                // after ping pair
    _Float16* wthi = (_Float16*)wsf;             // 5*262144 halves (655,360 fl)
    _Float16* wtlo = (_Float16*)(wsf + 655360);  // 5*262144 halves
    _Float16* cbhi = (_Float16*)(wsf + 1310720); // 262144 halves (131,072 fl)
    _Float16* cblo = (_Float16*)(wsf + 1441792); // 262144 halves
    float* cnorm = wsf + 1572864;                // 1024
    float* scsh  = cnorm + 1024;                 // 5 * 512
    float* part  = scsh + 2560;                  // 2 * 65536 (dead at VQ time)
    float* sums  = part + 131072;                // 262144
    float* nval  = sums + 262144;                // 16
    int*      ids  = (int*)(nval + 16);          // 131072
    unsigned* cnt  = (unsigned*)(ids + 131072);  // 1024
    int*      offs = (int*)(cnt + 1024);         // 1025
    int*      curs = offs + 1025;                // 1024
    int*      perm = curs + 1024;                // 131072
    int*      scode = (int*)part;                // reuse BN partial region

    hipMemsetAsync(cnt, 0, 1024 * sizeof(unsigned), stream);
    hipMemsetAsync(sums, 0, 262144 * sizeof(float), stream);

    // prep: split weights ([o][tap*256+ci]) + codebook + cnorm
    for (int i = 0; i < 5; i++)
        prep_w_split<<<1024, 256, 0, stream>>>(w[i + 2], wthi + (size_t)i * 262144,
                                               wtlo + (size_t)i * 262144);
    split8<<<128, 256, 0, stream>>>(codebook, cbhi, cblo, 32768);
    prep_cnorm<<<1024, 256, 0, stream>>>(codebook, cnorm);

    // layer 1: x -> ping halves (T=4097)
    conv1_kernel<<<dim3(129, 32), 256, 0, stream>>>(x, w[1], bias[1], pingH, pingL);
    bn_partial_h<<<256, 256, 0, stream>>>(pingH, pingL, 131104, part);
    bn_finalize<<<1, 256, 0, stream>>>(part, g[1], be[1], 1.f / 131104.f, scsh);
    bn_split_h<<<4096, 256, 0, stream>>>(pingH, pingL, scsh, 131104 * 32);

    // layer 2: ping -> pong
    conv_gemm_mfma<4097, 4096, 1, false><<<dim3(2, 1024), 256, 0, stream>>>(
        pingH, pingL, wthi, wtlo, bias[2], nullptr, pongH, pongL);
    bn_partial_h<<<256, 256, 0, stream>>>(pongH, pongL, 131072, part);
    bn_finalize<<<1, 256, 0, stream>>>(part, g[2], be[2], 1.f / 131072.f, scsh + 512);
    bn_split_h<<<4096, 256, 0, stream>>>(pongH, pongL, scsh + 512, 131072 * 32);

    // layer 3: pong -> ping
    conv_gemm_mfma<4096, 4097, 2, false><<<dim3(2, 1025), 256, 0, stream>>>(
        pongH, pongL, wthi + 262144, wtlo + 262144, bias[3], nullptr, pingH, pingL);
    bn_partial_h<<<256, 256, 0, stream>>>(pingH, pingL, 131104, part);
    bn_finalize<<<1, 256, 0, stream>>>(part, g[3], be[3], 1.f / 131104.f, scsh + 1024);
    bn_split_h<<<4096, 256, 0, stream>>>(pingH, pingL, scsh + 1024, 131104 * 32);

    // layer 4: ping -> pong
    conv_gemm_mfma<4097, 4096, 1, false><<<dim3(2, 1024), 256, 0, stream>>>(
        pingH, pingL, wthi + 524288, wtlo + 524288, bias[4], nullptr, pongH, pongL);
    bn_partial_h<<<256, 256, 0, stream>>>(pongH, pongL, 131072, part);
    bn_finalize<<<1, 256, 0, stream>>>(part, g[4], be[4], 1.f / 131072.f, scsh + 1536);
    bn_split_h<<<4096, 256, 0, stream>>>(pongH, pongL, scsh + 1536, 131072 * 32);

    // layer 5: pong -> ping
    conv_gemm_mfma<4096, 4097, 2, false><<<dim3(2, 1025), 256, 0, stream>>>(
        pongH, pongL, wthi + 786432, wtlo + 786432, bias[5], nullptr, pingH, pingL);
    bn_partial_h<<<256, 256, 0, stream>>>(pingH, pingL, 131104, part);
    bn_finalize<<<1, 256, 0, stream>>>(part, g[5], be[5], 1.f / 131104.f, scsh + 2048);
    bn_split_h<<<4096, 256, 0, stream>>>(pingH, pingL, scsh + 2048, 131104 * 32);

    // layer 6: ping -> z_e (fp32 out, no BN/relu)
    conv_gemm_mfma<4097, 4096, 1, true><<<dim3(2, 1024), 256, 0, stream>>>(
        pingH, pingL, wthi + 1048576, wtlo + 1048576, bias[6], z_e, nullptr, nullptr);

    // VQ
    split8<<<4096, 256, 0, stream>>>(z_e, pongH, pongL, 4194304);
    vq_argmin_mfma<<<1024, 256, 0, stream>>>(pongH, pongL, cbhi, cblo, cnorm, ids);
    vq_hist<<<512, 256, 0, stream>>>(ids, cnt);
    vq_scan<<<1, 1024, 0, stream>>>(cnt, offs, curs);
    vq_scatter<<<512, 256, 0, stream>>>(ids, curs, perm, scode);
    vq_gather_zq<<<32768, 256, 0, stream>>>(ids, codebook, z_q);
    vq_segsum<<<512, 256, 0, stream>>>(perm, scode, z_e, sums);
    vq_fin1<<<1, 1024, 0, stream>>>(cnt, ema_cs, ecs, nval);
    vq_fin2<<<1024, 256, 0, stream>>>(ema_w, sums, ecs, nval, cbout);
}

// Round 4
// 3203.433 us; speedup vs baseline: 2.2971x; 1.3603x over previous
//
#include <hip/hip_runtime.h>
#include <cstdint>
#include <cstddef>

// ===========================================================================
// VQ-VAE encoder: 6x conv1d(k=4) + BN(train) + relu chain, then VQ (argmin,
// EMA codebook update). B=32, T=4096, D=256, K=1024.
//
// R5: vq_hist / vq_scatter global-atomic hot-address serialization fix
// (R4b profile: vq_scatter 569us with ALL pipes idle = same-address RMW
// serialization on skewed code counts). Both kernels now build a per-block
// LDS histogram (parallel across 512 blocks) and issue at most one global
// atomic per (block, code): worst-case 512 serialized RMWs per address
// instead of ~cluster-size. Scatter ranks = LDS-local rank + per-block
// reserved base; fills the same per-code ranges, so scode/perm semantics
// are unchanged.
// ===========================================================================

typedef _Float16 half8 __attribute__((ext_vector_type(8)));
typedef float f32x4 __attribute__((ext_vector_type(4)));

#define MFMA16(a, b, c) __builtin_amdgcn_mfma_f32_16x16x32_f16((a), (b), (c), 0, 0, 0)
#define INV2048 4.8828125e-4f

__device__ __forceinline__ void splitf(float v, _Float16& h, _Float16& l)
{
    _Float16 hh = (_Float16)v;
    h = hh;
    l = (_Float16)((v - (float)hh) * 2048.0f);
}
__device__ __forceinline__ float joinf(_Float16 h, _Float16 l)
{
    return (float)h + (float)l * INV2048;
}

// ---------------------------------------------------------------------------
// conv1: x (32,4096,12) -> Y halves (32,4097,256), pad=2, k=4.
// ---------------------------------------------------------------------------
__global__ __launch_bounds__(256)
void conv1_kernel(const float* __restrict__ x, const float* __restrict__ w1,
                  const float* __restrict__ b1, _Float16* __restrict__ YH,
                  _Float16* __restrict__ YL)
{
    const int b  = blockIdx.y;
    const int t0 = blockIdx.x * 32;
    const int oc = threadIdx.x;
    __shared__ float xl[35 * 12];
    for (int idx = threadIdx.x; idx < 420; idx += 256) {
        int tt = t0 - 2 + idx / 12;
        int i  = idx % 12;
        xl[idx] = (tt >= 0 && tt < 4096) ? x[((size_t)b * 4096 + tt) * 12 + i] : 0.f;
    }
    float w[48];
#pragma unroll
    for (int q = 0; q < 12; q++)
        *(float4*)&w[q * 4] = *(const float4*)(w1 + (size_t)oc * 48 + q * 4);
    __syncthreads();
    const float bias = b1[oc];
    for (int dt = 0; dt < 32; dt++) {
        int t = t0 + dt;
        if (t >= 4097) break;
        float a = bias;
#pragma unroll
        for (int i = 0; i < 12; i++)
#pragma unroll
            for (int k = 0; k < 4; k++)
                a = fmaf(xl[(dt + k) * 12 + i], w[i * 4 + k], a);
        _Float16 h, l;
        splitf(a, h, l);
        const size_t o = ((size_t)b * 4097 + t) * 256 + oc;
        YH[o] = h;
        YL[o] = l;
    }
}

// ---------------------------------------------------------------------------
// Deterministic BN stats over split-half tensors.
// ---------------------------------------------------------------------------
__global__ __launch_bounds__(256)
void bn_partial_h(const _Float16* __restrict__ YH, const _Float16* __restrict__ YL,
                  int M, float* __restrict__ part)
{
    const int j = blockIdx.x;   // 0..255
    const int c = threadIdx.x;  // channel
    const int chunk = (M + 255) / 256;
    int r0 = j * chunk;
    int r1 = r0 + chunk; if (r1 > M) r1 = M;
    float s = 0.f, s2 = 0.f;
    for (int r = r0; r < r1; r++) {
        const size_t o = ((size_t)r << 8) + c;
        float v = joinf(YH[o], YL[o]);
        s += v;
        s2 = fmaf(v, v, s2);
    }
    part[j * 256 + c]         = s;
    part[65536 + j * 256 + c] = s2;
}

__global__ __launch_bounds__(256)
void bn_finalize(const float* __restrict__ part, const float* __restrict__ g,
                 const float* __restrict__ be, float invM, float* __restrict__ scsh)
{
    const int c = threadIdx.x;
    float s = 0.f, s2 = 0.f;
    for (int j = 0; j < 256; j++) {
        s  += part[j * 256 + c];
        s2 += part[65536 + j * 256 + c];
    }
    float mean = s * invM;
    float var  = fmaf(s2, invM, -mean * mean);
    float sc   = g[c] * rsqrtf(var + 1e-5f);
    scsh[c]       = sc;
    scsh[256 + c] = fmaf(-mean, sc, be[c]);
}

// ---------------------------------------------------------------------------
// In-place BN+relu+re-split on a split-half tensor. N8 = numel/8.
// ---------------------------------------------------------------------------
__global__ __launch_bounds__(256)
void bn_split_h(_Float16* __restrict__ YH, _Float16* __restrict__ YL,
                const float* __restrict__ scsh, int N8)
{
    int idx = blockIdx.x * 256 + threadIdx.x;
    const int stride = gridDim.x * 256;
    for (; idx < N8; idx += stride) {
        const size_t e0 = (size_t)idx * 8;
        const int ci0 = (int)(e0 & 255);
        half8 h = *(half8*)(YH + e0);
        half8 l = *(half8*)(YL + e0);
        float4 scA = *(const float4*)(scsh + ci0);
        float4 scB = *(const float4*)(scsh + ci0 + 4);
        float4 shA = *(const float4*)(scsh + 256 + ci0);
        float4 shB = *(const float4*)(scsh + 256 + ci0 + 4);
        float sc[8] = {scA.x, scA.y, scA.z, scA.w, scB.x, scB.y, scB.z, scB.w};
        float sh[8] = {shA.x, shA.y, shA.z, shA.w, shB.x, shB.y, shB.z, shB.w};
#pragma unroll
        for (int e = 0; e < 8; e++) {
            float v = joinf(h[e], l[e]);
            v = fmaxf(fmaf(v, sc[e], sh[e]), 0.f);
            _Float16 hh, ll;
            splitf(v, hh, ll);
            h[e] = hh;
            l[e] = ll;
        }
        *(half8*)(YH + e0) = h;
        *(half8*)(YL + e0) = l;
    }
}

// ---------------------------------------------------------------------------
// Plain fp32 -> split halves (z_e, codebook). N8 = numel/8.
// ---------------------------------------------------------------------------
__global__ __launch_bounds__(256)
void split8(const float* __restrict__ Z, _Float16* __restrict__ ZH,
            _Float16* __restrict__ ZL, int N8)
{
    int idx = blockIdx.x * 256 + threadIdx.x;
    const int stride = gridDim.x * 256;
    for (; idx < N8; idx += stride) {
        const size_t e0 = (size_t)idx * 8;
        float4 a = *(const float4*)(Z + e0);
        float4 b = *(const float4*)(Z + e0 + 4);
        float v[8] = {a.x, a.y, a.z, a.w, b.x, b.y, b.z, b.w};
        half8 h, l;
#pragma unroll
        for (int e = 0; e < 8; e++) {
            _Float16 hh, ll;
            splitf(v[e], hh, ll);
            h[e] = hh;
            l[e] = ll;
        }
        *(half8*)(ZH + e0) = h;
        *(half8*)(ZL + e0) = l;
    }
}

// w (256,256,4) [o][ci][tap] -> split halves at [o][tap*256+ci]
__global__ __launch_bounds__(256)
void prep_w_split(const float* __restrict__ w, _Float16* __restrict__ hi,
                  _Float16* __restrict__ lo)
{
    int idx = blockIdx.x * 256 + threadIdx.x;  // 262144
    int o   = idx >> 10, rem = idx & 1023;
    int tap = rem >> 8,  ci  = rem & 255;
    float v = w[((size_t)o << 10) + (ci << 2) + tap];
    _Float16 h, l;
    splitf(v, h, l);
    hi[idx] = h;
    lo[idx] = l;
}

// per-code squared norms (fp32 exact)
__global__ __launch_bounds__(256)
void prep_cnorm(const float* __restrict__ cb, float* __restrict__ cnorm)
{
    const int k = blockIdx.x;   // 1024
    const int d = threadIdx.x;  // 256
    float v = cb[((size_t)k << 8) + d];
    __shared__ float sm[256];
    sm[d] = v * v;
    __syncthreads();
    for (int off = 128; off > 0; off >>= 1) {
        if (d < off) sm[d] += sm[d + off];
        __syncthreads();
    }
    if (d == 0) cnorm[k] = sm[0];
}

// ---------------------------------------------------------------------------
// conv2..6 as split-fp16 MFMA GEMM, 128x128 tile, BK=32, register-prefetch
// pipeline. K index: k = tap*256 + ci (A-stage = contiguous 64B row slice,
// matches the prep_w_split weight layout). LDS [row][32 halves] with
// half_idx ^= (row&7)<<3 swizzle.
// ---------------------------------------------------------------------------
template<int T_IN, int T_OUT, int PAD, bool F32OUT>
__global__ __launch_bounds__(256)
void conv_gemm_mfma(const _Float16* __restrict__ XH, const _Float16* __restrict__ XL,
                    const _Float16* __restrict__ WH, const _Float16* __restrict__ WL,
                    const float* __restrict__ bias, float* __restrict__ Yf,
                    _Float16* __restrict__ YH, _Float16* __restrict__ YL)
{
    constexpr int M = 32 * T_OUT;
    __shared__ _Float16 AsH[4096], AsL[4096], BsH[4096], BsL[4096];

    const int tid  = threadIdx.x;
    const int lane = tid & 63;
    const int wv   = tid >> 6;     // wave 0..3 -> rows 32*wv..32*wv+31
    const int fr   = lane & 15;
    const int kgf  = lane >> 4;
    const int m0 = blockIdx.y * 128;
    const int n0 = blockIdx.x * 128;

    const int haBase = wv * 1024 + ((fr * 32 + kgf * 8) ^ ((fr & 7) << 3));
    const int hbBase = (fr * 32 + kgf * 8) ^ ((fr & 7) << 3);

    // staging tasks: u in {0,1}: row = (tid>>2)+64u, 16B granule skg = tid&3
    const int skg = tid & 3;
    int wOff[2], tOut[2];
    long long aBase[2];
    size_t bBase[2];
    bool mok[2];
#pragma unroll
    for (int u = 0; u < 2; u++) {
        int r = (tid >> 2) + 64 * u;
        wOff[u] = (r * 32 + skg * 8) ^ ((r & 7) << 3);
        int m = m0 + r;
        mok[u] = (m < M);
        int b;
        if (T_OUT == 4096) b = m >> 12;
        else               b = (m - (m >> 12)) >> 12;   // m/4097
        int t = m - b * T_OUT;
        tOut[u]  = t;
        aBase[u] = (((long long)b * T_IN + t) << 8) + (skg << 3);
        bBase[u] = (((size_t)(n0 + r)) << 10) + (skg << 3);
    }

    half8 rAH[2], rAL[2], rBH[2], rBL[2];
    const half8 hz = {(_Float16)0, (_Float16)0, (_Float16)0, (_Float16)0,
                      (_Float16)0, (_Float16)0, (_Float16)0, (_Float16)0};

    auto LOAD = [&](int s) {
        const int tap = s >> 3;
        const int ci0 = (s & 7) << 5;
        const int dt  = tap - PAD;
#pragma unroll
        for (int u = 0; u < 2; u++) {
            const int ti = tOut[u] + dt;
            if (mok[u] && ti >= 0 && ti < T_IN) {
                const long long ga = aBase[u] + ((long long)dt << 8) + ci0;
                rAH[u] = *(const half8*)(XH + ga);
                rAL[u] = *(const half8*)(XL + ga);
            } else {
                rAH[u] = hz;
                rAL[u] = hz;
            }
            const size_t gb = bBase[u] + ((size_t)s << 5);
            rBH[u] = *(const half8*)(WH + gb);
            rBL[u] = *(const half8*)(WL + gb);
        }
    };

    f32x4 acc1[2][8], acc2[2][8];
#pragma unroll
    for (int i = 0; i < 2; i++)
#pragma unroll
        for (int j = 0; j < 8; j++) {
            acc1[i][j] = (f32x4){0.f, 0.f, 0.f, 0.f};
            acc2[i][j] = (f32x4){0.f, 0.f, 0.f, 0.f};
        }

    LOAD(0);
    for (int s = 0; s < 32; s++) {
        *(half8*)&AsH[wOff[0]] = rAH[0];
        *(half8*)&AsH[wOff[1]] = rAH[1];
        *(half8*)&AsL[wOff[0]] = rAL[0];
        *(half8*)&AsL[wOff[1]] = rAL[1];
        *(half8*)&BsH[wOff[0]] = rBH[0];
        *(half8*)&BsH[wOff[1]] = rBH[1];
        *(half8*)&BsL[wOff[0]] = rBL[0];
        *(half8*)&BsL[wOff[1]] = rBL[1];
        __syncthreads();
        if (s + 1 < 32) LOAD(s + 1);   // prefetch under the MFMA phase
        half8 ah0 = *(const half8*)&AsH[haBase];
        half8 ah1 = *(const half8*)&AsH[haBase + 512];
        half8 al0 = *(const half8*)&AsL[haBase];
        half8 al1 = *(const half8*)&AsL[haBase + 512];
#pragma unroll
        for (int j = 0; j < 8; j++) {
            half8 bh = *(const half8*)&BsH[hbBase + j * 512];
            half8 bl = *(const half8*)&BsL[hbBase + j * 512];
            acc1[0][j] = MFMA16(ah0, bh, acc1[0][j]);
            acc2[0][j] = MFMA16(ah0, bl, acc2[0][j]);
            acc2[0][j] = MFMA16(al0, bh, acc2[0][j]);
            acc1[1][j] = MFMA16(ah1, bh, acc1[1][j]);
            acc2[1][j] = MFMA16(ah1, bl, acc2[1][j]);
            acc2[1][j] = MFMA16(al1, bh, acc2[1][j]);
        }
        __syncthreads();
    }

    // ---- epilogue: C = acc1 + acc2/2048 + bias ----
    float bj[8];
#pragma unroll
    for (int j = 0; j < 8; j++) bj[j] = bias[n0 + j * 16 + fr];
#pragma unroll
    for (int i = 0; i < 2; i++)
#pragma unroll
        for (int q = 0; q < 4; q++) {
            const int m = m0 + wv * 32 + i * 16 + kgf * 4 + q;
            if (m < M) {
#pragma unroll
                for (int j = 0; j < 8; j++) {
                    float vv = acc1[i][j][q] + acc2[i][j][q] * INV2048 + bj[j];
                    const size_t o = ((size_t)m << 8) + n0 + j * 16 + fr;
                    if constexpr (F32OUT) {
                        Yf[o] = vv;
                    } else {
                        _Float16 h, l;
                        splitf(vv, h, l);
                        YH[o] = h;
                        YL[o] = l;
                    }
                }
            }
        }
}

// ---------------------------------------------------------------------------
// VQ argmin via split-fp16 MFMA with the same prefetch pipeline.
// ---------------------------------------------------------------------------
__global__ __launch_bounds__(256)
void vq_argmin_mfma(const _Float16* __restrict__ ZH, const _Float16* __restrict__ ZL,
                    const _Float16* __restrict__ CH, const _Float16* __restrict__ CL,
                    const float* __restrict__ cnorm, int* __restrict__ ids)
{
    __shared__ _Float16 AsH[4096], AsL[4096], BsH[4096], BsL[4096];

    const int tid  = threadIdx.x;
    const int lane = tid & 63;
    const int wv   = tid >> 6;
    const int fr   = lane & 15;
    const int kgf  = lane >> 4;
    const int m0 = blockIdx.x * 128;

    const int haBase = wv * 1024 + ((fr * 32 + kgf * 8) ^ ((fr & 7) << 3));
    const int hbBase = (fr * 32 + kgf * 8) ^ ((fr & 7) << 3);

    const int skg = tid & 3;
    int wOff[2];
    size_t aBase[2], bBase[2];
#pragma unroll
    for (int u = 0; u < 2; u++) {
        int r = (tid >> 2) + 64 * u;
        wOff[u]  = (r * 32 + skg * 8) ^ ((r & 7) << 3);
        aBase[u] = (((size_t)(m0 + r)) << 8) + (skg << 3);
        bBase[u] = (((size_t)r) << 8) + (skg << 3);
    }

    half8 rAH[2], rAL[2], rBH[2], rBL[2];

    auto LOADV = [&](int ss) {
        const int nt = ss >> 3;
        const int dd = (ss & 7) << 5;
#pragma unroll
        for (int u = 0; u < 2; u++) {
            const size_t ga = aBase[u] + dd;
            rAH[u] = *(const half8*)(ZH + ga);
            rAL[u] = *(const half8*)(ZL + ga);
            const size_t gb = bBase[u] + ((size_t)nt << 15) + dd;
            rBH[u] = *(const half8*)(CH + gb);
            rBL[u] = *(const half8*)(CL + gb);
        }
    };

    float bv[2][4];
    int   bk[2][4];
#pragma unroll
    for (int i = 0; i < 2; i++)
#pragma unroll
        for (int q = 0; q < 4; q++) { bv[i][q] = 3.4e38f; bk[i][q] = 0; }

    f32x4 acc1[2][8], acc2[2][8];

    LOADV(0);
    for (int nt = 0; nt < 8; nt++) {
#pragma unroll
        for (int i = 0; i < 2; i++)
#pragma unroll
            for (int j = 0; j < 8; j++) {
                acc1[i][j] = (f32x4){0.f, 0.f, 0.f, 0.f};
                acc2[i][j] = (f32x4){0.f, 0.f, 0.f, 0.f};
            }
        for (int dstep = 0; dstep < 8; dstep++) {
            const int ss = nt * 8 + dstep;
            *(half8*)&AsH[wOff[0]] = rAH[0];
            *(half8*)&AsH[wOff[1]] = rAH[1];
            *(half8*)&AsL[wOff[0]] = rAL[0];
            *(half8*)&AsL[wOff[1]] = rAL[1];
            *(half8*)&BsH[wOff[0]] = rBH[0];
            *(half8*)&BsH[wOff[1]] = rBH[1];
            *(half8*)&BsL[wOff[0]] = rBL[0];
            *(half8*)&BsL[wOff[1]] = rBL[1];
            __syncthreads();
            if (ss + 1 < 64) LOADV(ss + 1);
            half8 ah0 = *(const half8*)&AsH[haBase];
            half8 ah1 = *(const half8*)&AsH[haBase + 512];
            half8 al0 = *(const half8*)&AsL[haBase];
            half8 al1 = *(const half8*)&AsL[haBase + 512];
#pragma unroll
            for (int j = 0; j < 8; j++) {
                half8 bh = *(const half8*)&BsH[hbBase + j * 512];
                half8 bl = *(const half8*)&BsL[hbBase + j * 512];
                acc1[0][j] = MFMA16(ah0, bh, acc1[0][j]);
                acc2[0][j] = MFMA16(ah0, bl, acc2[0][j]);
                acc2[0][j] = MFMA16(al0, bh, acc2[0][j]);
                acc1[1][j] = MFMA16(ah1, bh, acc1[1][j]);
                acc2[1][j] = MFMA16(ah1, bl, acc2[1][j]);
                acc2[1][j] = MFMA16(al1, bh, acc2[1][j]);
            }
            __syncthreads();
        }
        // running min update for this 128-code tile
        const int n0t = nt * 128;
#pragma unroll
        for (int j = 0; j < 8; j++) {
            const int code = n0t + j * 16 + fr;
            const float cn = cnorm[code];
#pragma unroll
            for (int i = 0; i < 2; i++)
#pragma unroll
                for (int q = 0; q < 4; q++) {
                    float s = fmaf(-2.f, acc1[i][j][q] + acc2[i][j][q] * INV2048, cn);
                    if (s < bv[i][q] || (s == bv[i][q] && code < bk[i][q])) {
                        bv[i][q] = s; bk[i][q] = code;
                    }
                }
        }
    }

    // reduce across the 16 frag-cols
#pragma unroll
    for (int i = 0; i < 2; i++)
#pragma unroll
        for (int q = 0; q < 4; q++) {
            float v = bv[i][q];
            int   k = bk[i][q];
            for (int msk = 1; msk < 16; msk <<= 1) {
                float ov = __shfl_xor(v, msk, 64);
                int   ok = __shfl_xor(k, msk, 64);
                if (ov < v || (ov == v && ok < k)) { v = ov; k = ok; }
            }
            if (fr == 0) ids[m0 + wv * 32 + i * 16 + kgf * 4 + q] = k;
        }
}

// ---------------------------------------------------------------------------
// Counting sort with LDS-privatized histograms (fix same-address RMW
// serialization: <=512 global atomics per code instead of cluster-size).
// ---------------------------------------------------------------------------
__global__ __launch_bounds__(256)
void vq_hist(const int* __restrict__ ids, unsigned* __restrict__ cnt)
{
    __shared__ unsigned lc[1024];
    const int t = threadIdx.x;
#pragma unroll
    for (int u = 0; u < 4; u++) lc[t + 256 * u] = 0u;
    __syncthreads();
    const int m = blockIdx.x * 256 + t;
    atomicAdd(&lc[ids[m]], 1u);
    __syncthreads();
#pragma unroll
    for (int u = 0; u < 4; u++) {
        const int c = t + 256 * u;
        const unsigned h = lc[c];
        if (h) atomicAdd(&cnt[c], h);
    }
}

__global__ __launch_bounds__(1024)
void vq_scan(const unsigned* __restrict__ cnt, int* __restrict__ offs, int* __restrict__ curs)
{
    __shared__ int sm[1024];
    const int k = threadIdx.x;
    const int c = (int)cnt[k];
    sm[k] = c;
    __syncthreads();
    for (int off = 1; off < 1024; off <<= 1) {
        int v = (k >= off) ? sm[k - off] : 0;
        __syncthreads();
        sm[k] += v;
        __syncthreads();
    }
    int exc = sm[k] - c;
    offs[k] = exc;
    curs[k] = exc;
    if (k == 1023) offs[1024] = sm[k];
}

__global__ __launch_bounds__(256)
void vq_scatter(const int* __restrict__ ids, int* __restrict__ curs,
                int* __restrict__ perm, int* __restrict__ scode)
{
    __shared__ int lcnt[1024];
    __shared__ int lbase[1024];
    const int t = threadIdx.x;
#pragma unroll
    for (int u = 0; u < 4; u++) lcnt[t + 256 * u] = 0;
    __syncthreads();
    const int m = blockIdx.x * 256 + t;
    const int id = ids[m];
    const int lrank = atomicAdd(&lcnt[id], 1);   // LDS atomic: local rank
    __syncthreads();
#pragma unroll
    for (int u = 0; u < 4; u++) {
        const int c = t + 256 * u;
        const int h = lcnt[c];
        if (h) lbase[c] = atomicAdd(&curs[c], h); // one global RMW per (block, code)
    }
    __syncthreads();
    const int pos = lbase[id] + lrank;
    perm[pos]  = m;
    scode[pos] = id;
}

// ---------------------------------------------------------------------------
// z_q gather: fully parallel, float4/lane. 4 rows per block (64 lanes/row).
// ---------------------------------------------------------------------------
__global__ __launch_bounds__(256)
void vq_gather_zq(const int* __restrict__ ids, const float* __restrict__ cb,
                  float* __restrict__ zq)
{
    const int row = blockIdx.x * 4 + (threadIdx.x >> 6);
    const int d4  = (threadIdx.x & 63) << 2;
    const int id  = ids[row];
    *(float4*)(zq + ((size_t)row << 8) + d4) =
        *(const float4*)(cb + ((size_t)id << 8) + d4);
}

__global__ __launch_bounds__(256)
void vq_segsum(const int* __restrict__ perm, const int* __restrict__ scode,
               const float* __restrict__ Z, float* __restrict__ sums)
{
    __shared__ int pm[256];
    __shared__ int cd[256];
    const int p0 = blockIdx.x * 256;
    const int d  = threadIdx.x;
    pm[d] = perm[p0 + d];
    cd[d] = scode[p0 + d];
    __syncthreads();
    float s = 0.f;
    int cur = cd[0];
    for (int i = 0; i < 256; i++) {
        int c = cd[i];
        float v = Z[((size_t)pm[i] << 8) + d];
        if (c != cur) {
            atomicAdd(&sums[((size_t)cur << 8) + d], s);
            s = 0.f;
            cur = c;
        }
        s += v;
    }
    atomicAdd(&sums[((size_t)cur << 8) + d], s);
}

__global__ __launch_bounds__(1024)
void vq_fin1(const unsigned* __restrict__ cnt, const float* __restrict__ ema_cs,
             float* __restrict__ ecs, float* __restrict__ nval)
{
    __shared__ float sm[1024];
    const int k = threadIdx.x;
    float e = fmaf(ema_cs[k], 0.99f, 0.01f * (float)cnt[k]);
    ecs[k] = e;
    sm[k] = e;
    __syncthreads();
    for (int off = 512; off > 0; off >>= 1) {
        if (k < off) sm[k] += sm[k + off];
        __syncthreads();
    }
    if (k == 0) nval[0] = sm[0];
}

__global__ __launch_bounds__(256)
void vq_fin2(const float* __restrict__ ema_w, const float* __restrict__ sums,
             const float* __restrict__ ecs, const float* __restrict__ nval,
             float* __restrict__ cbout)
{
    const int k = blockIdx.x, d = threadIdx.x;
    const float n = nval[0];
    const float sm = ((ecs[k] + 1e-5f) / (n + 0.01024f)) * n;
    const size_t idx = ((size_t)k << 8) + d;
    cbout[idx] = fmaf(ema_w[idx], 0.99f, 0.01f * sums[idx]) / sm;
}

// ===========================================================================
extern "C" void kernel_launch(void* const* d_in, const int* in_sizes, int n_in,
                              void* d_out, int out_size, void* d_ws, size_t ws_size,
                              hipStream_t stream)
{
    (void)in_sizes; (void)n_in; (void)out_size; (void)ws_size;

    const float* x = (const float*)d_in[0];
    const float* w[7]; const float* bias[7];
    for (int i = 1; i <= 6; i++) {
        w[i]    = (const float*)d_in[1 + 2 * (i - 1)];
        bias[i] = (const float*)d_in[2 + 2 * (i - 1)];
    }
    const float* g[6]; const float* be[6];
    for (int i = 1; i <= 5; i++) {
        g[i]  = (const float*)d_in[13 + 2 * (i - 1)];
        be[i] = (const float*)d_in[14 + 2 * (i - 1)];
    }
    const float* codebook = (const float*)d_in[23];
    const float* ema_w    = (const float*)d_in[24];
    const float* ema_cs   = (const float*)d_in[25];

    float* out   = (float*)d_out;
    float* z_e   = out;                      // 32*4096*256
    float* z_q   = out + 33554432;           // 32*4096*256
    float* cbout = out + 67108864;           // 1024*256
    float* ecs   = out + 67371008;           // 1024

    // ping pair (4097-sized layers) in ws; pong pair (4096-sized) in z_q region
    float* ws = (float*)d_ws;
    _Float16* pingH = (_Float16*)ws;             // 131104*256 = 33,562,624 halves
    _Float16* pingL = pingH + 33562624;
    _Float16* pongH = (_Float16*)z_q;            // 131072*256 halves (exact fit)
    _Float16* pongL = pongH + 33554432;

    float* wsf   = ws + 33562624;                // after ping pair
    _Float16* wthi = (_Float16*)wsf;             // 5*262144 halves (655,360 fl)
    _Float16* wtlo = (_Float16*)(wsf + 655360);  // 5*262144 halves
    _Float16* cbhi = (_Float16*)(wsf + 1310720); // 262144 halves (131,072 fl)
    _Float16* cblo = (_Float16*)(wsf + 1441792); // 262144 halves
    float* cnorm = wsf + 1572864;                // 1024
    float* scsh  = cnorm + 1024;                 // 5 * 512
    float* part  = scsh + 2560;                  // 2 * 65536 (dead at VQ time)
    float* sums  = part + 131072;                // 262144
    float* nval  = sums + 262144;                // 16
    int*      ids  = (int*)(nval + 16);          // 131072
    unsigned* cnt  = (unsigned*)(ids + 131072);  // 1024
    int*      offs = (int*)(cnt + 1024);         // 1025
    int*      curs = offs + 1025;                // 1024
    int*      perm = curs + 1024;                // 131072
    int*      scode = (int*)part;                // reuse BN partial region

    hipMemsetAsync(cnt, 0, 1024 * sizeof(unsigned), stream);
    hipMemsetAsync(sums, 0, 262144 * sizeof(float), stream);

    // prep: split weights ([o][tap*256+ci]) + codebook + cnorm
    for (int i = 0; i < 5; i++)
        prep_w_split<<<1024, 256, 0, stream>>>(w[i + 2], wthi + (size_t)i * 262144,
                                               wtlo + (size_t)i * 262144);
    split8<<<128, 256, 0, stream>>>(codebook, cbhi, cblo, 32768);
    prep_cnorm<<<1024, 256, 0, stream>>>(codebook, cnorm);

    // layer 1: x -> ping halves (T=4097)
    conv1_kernel<<<dim3(129, 32), 256, 0, stream>>>(x, w[1], bias[1], pingH, pingL);
    bn_partial_h<<<256, 256, 0, stream>>>(pingH, pingL, 131104, part);
    bn_finalize<<<1, 256, 0, stream>>>(part, g[1], be[1], 1.f / 131104.f, scsh);
    bn_split_h<<<4096, 256, 0, stream>>>(pingH, pingL, scsh, 131104 * 32);

    // layer 2: ping -> pong
    conv_gemm_mfma<4097, 4096, 1, false><<<dim3(2, 1024), 256, 0, stream>>>(
        pingH, pingL, wthi, wtlo, bias[2], nullptr, pongH, pongL);
    bn_partial_h<<<256, 256, 0, stream>>>(pongH, pongL, 131072, part);
    bn_finalize<<<1, 256, 0, stream>>>(part, g[2], be[2], 1.f / 131072.f, scsh + 512);
    bn_split_h<<<4096, 256, 0, stream>>>(pongH, pongL, scsh + 512, 131072 * 32);

    // layer 3: pong -> ping
    conv_gemm_mfma<4096, 4097, 2, false><<<dim3(2, 1025), 256, 0, stream>>>(
        pongH, pongL, wthi + 262144, wtlo + 262144, bias[3], nullptr, pingH, pingL);
    bn_partial_h<<<256, 256, 0, stream>>>(pingH, pingL, 131104, part);
    bn_finalize<<<1, 256, 0, stream>>>(part, g[3], be[3], 1.f / 131104.f, scsh + 1024);
    bn_split_h<<<4096, 256, 0, stream>>>(pingH, pingL, scsh + 1024, 131104 * 32);

    // layer 4: ping -> pong
    conv_gemm_mfma<4097, 4096, 1, false><<<dim3(2, 1024), 256, 0, stream>>>(
        pingH, pingL, wthi + 524288, wtlo + 524288, bias[4], nullptr, pongH, pongL);
    bn_partial_h<<<256, 256, 0, stream>>>(pongH, pongL, 131072, part);
    bn_finalize<<<1, 256, 0, stream>>>(part, g[4], be[4], 1.f / 131072.f, scsh + 1536);
    bn_split_h<<<4096, 256, 0, stream>>>(pongH, pongL, scsh + 1536, 131072 * 32);

    // layer 5: pong -> ping
    conv_gemm_mfma<4096, 4097, 2, false><<<dim3(2, 1025), 256, 0, stream>>>(
        pongH, pongL, wthi + 786432, wtlo + 786432, bias[5], nullptr, pingH, pingL);
    bn_partial_h<<<256, 256, 0, stream>>>(pingH, pingL, 131104, part);
    bn_finalize<<<1, 256, 0, stream>>>(part, g[5], be[5], 1.f / 131104.f, scsh + 2048);
    bn_split_h<<<4096, 256, 0, stream>>>(pingH, pingL, scsh + 2048, 131104 * 32);

    // layer 6: ping -> z_e (fp32 out, no BN/relu)
    conv_gemm_mfma<4097, 4096, 1, true><<<dim3(2, 1024), 256, 0, stream>>>(
        pingH, pingL, wthi + 1048576, wtlo + 1048576, bias[6], z_e, nullptr, nullptr);

    // VQ
    split8<<<4096, 256, 0, stream>>>(z_e, pongH, pongL, 4194304);
    vq_argmin_mfma<<<1024, 256, 0, stream>>>(pongH, pongL, cbhi, cblo, cnorm, ids);
    vq_hist<<<512, 256, 0, stream>>>(ids, cnt);
    vq_scan<<<1, 1024, 0, stream>>>(cnt, offs, curs);
    vq_scatter<<<512, 256, 0, stream>>>(ids, curs, perm, scode);
    vq_gather_zq<<<32768, 256, 0, stream>>>(ids, codebook, z_q);
    vq_segsum<<<512, 256, 0, stream>>>(perm, scode, z_e, sums);
    vq_fin1<<<1, 1024, 0, stream>>>(cnt, ema_cs, ecs, nval);
    vq_fin2<<<1024, 256, 0, stream>>>(ema_w, sums, ecs, nval, cbout);
}

// Round 6
// 3191.694 us; speedup vs baseline: 2.3055x; 1.0037x over previous
//
#include <hip/hip_runtime.h>
#include <cstdint>
#include <cstddef>

// ===========================================================================
// VQ-VAE encoder: 6x conv1d(k=4) + BN(train) + relu chain, then VQ (argmin,
// EMA codebook update). B=32, T=4096, D=256, K=1024.
//
// R6b: R6 with brace fix in vq_argmin_mfma (running-min j-loop was unclosed).
// LDS-throughput fix (R5: MfmaUtil 19%, LDS traffic 112KB/block-step vs
// 233cyc MFMA wall). GEMM geometry: 4 waves in 2x2, wave tile 64x64.
//  - A fragments load DIRECTLY from global (wave-private rows; no LDS write
//    or read for A), prefetched 1 step ahead into ping-pong register sets.
//  - B double-buffered in LDS, 1 barrier/step, read-amplification x4 -> x2.
//  - BN stats fused into conv epilogue (LDS reduce + per-block atomics);
//    bn_partial_h full-tensor pass needed only for layer 1.
// Split numerics unchanged: a = hi + lo/2048 (fp16), C = Ahi*Bhi +
// (Ahi*Blo' + Alo'*Bhi)/2048.
// ===========================================================================

typedef _Float16 half8 __attribute__((ext_vector_type(8)));
typedef float f32x4 __attribute__((ext_vector_type(4)));

#define MFMA16(a, b, c) __builtin_amdgcn_mfma_f32_16x16x32_f16((a), (b), (c), 0, 0, 0)
#define INV2048 4.8828125e-4f

__device__ __forceinline__ void splitf(float v, _Float16& h, _Float16& l)
{
    _Float16 hh = (_Float16)v;
    h = hh;
    l = (_Float16)((v - (float)hh) * 2048.0f);
}
__device__ __forceinline__ float joinf(_Float16 h, _Float16 l)
{
    return (float)h + (float)l * INV2048;
}

// ---------------------------------------------------------------------------
// conv1: x (32,4096,12) -> Y halves (32,4097,256), pad=2, k=4.
// ---------------------------------------------------------------------------
__global__ __launch_bounds__(256)
void conv1_kernel(const float* __restrict__ x, const float* __restrict__ w1,
                  const float* __restrict__ b1, _Float16* __restrict__ YH,
                  _Float16* __restrict__ YL)
{
    const int b  = blockIdx.y;
    const int t0 = blockIdx.x * 32;
    const int oc = threadIdx.x;
    __shared__ float xl[35 * 12];
    for (int idx = threadIdx.x; idx < 420; idx += 256) {
        int tt = t0 - 2 + idx / 12;
        int i  = idx % 12;
        xl[idx] = (tt >= 0 && tt < 4096) ? x[((size_t)b * 4096 + tt) * 12 + i] : 0.f;
    }
    float w[48];
#pragma unroll
    for (int q = 0; q < 12; q++)
        *(float4*)&w[q * 4] = *(const float4*)(w1 + (size_t)oc * 48 + q * 4);
    __syncthreads();
    const float bias = b1[oc];
    for (int dt = 0; dt < 32; dt++) {
        int t = t0 + dt;
        if (t >= 4097) break;
        float a = bias;
#pragma unroll
        for (int i = 0; i < 12; i++)
#pragma unroll
            for (int k = 0; k < 4; k++)
                a = fmaf(xl[(dt + k) * 12 + i], w[i * 4 + k], a);
        _Float16 h, l;
        splitf(a, h, l);
        const size_t o = ((size_t)b * 4097 + t) * 256 + oc;
        YH[o] = h;
        YL[o] = l;
    }
}

// ---------------------------------------------------------------------------
// Deterministic BN stats over split-half tensors (layer 1 only now).
// ---------------------------------------------------------------------------
__global__ __launch_bounds__(256)
void bn_partial_h(const _Float16* __restrict__ YH, const _Float16* __restrict__ YL,
                  int M, float* __restrict__ part)
{
    const int j = blockIdx.x;   // 0..255
    const int c = threadIdx.x;  // channel
    const int chunk = (M + 255) / 256;
    int r0 = j * chunk;
    int r1 = r0 + chunk; if (r1 > M) r1 = M;
    float s = 0.f, s2 = 0.f;
    for (int r = r0; r < r1; r++) {
        const size_t o = ((size_t)r << 8) + c;
        float v = joinf(YH[o], YL[o]);
        s += v;
        s2 = fmaf(v, v, s2);
    }
    part[j * 256 + c]         = s;
    part[65536 + j * 256 + c] = s2;
}

__global__ __launch_bounds__(256)
void bn_finalize(const float* __restrict__ part, const float* __restrict__ g,
                 const float* __restrict__ be, float invM, float* __restrict__ scsh)
{
    const int c = threadIdx.x;
    float s = 0.f, s2 = 0.f;
    for (int j = 0; j < 256; j++) {
        s  += part[j * 256 + c];
        s2 += part[65536 + j * 256 + c];
    }
    float mean = s * invM;
    float var  = fmaf(s2, invM, -mean * mean);
    float sc   = g[c] * rsqrtf(var + 1e-5f);
    scsh[c]       = sc;
    scsh[256 + c] = fmaf(-mean, sc, be[c]);
}

// Finalize from fused conv stats (part2[c] = sum, part2[256+c] = sumsq).
__global__ __launch_bounds__(256)
void bn_finalize2(const float* __restrict__ part2, const float* __restrict__ g,
                  const float* __restrict__ be, float invM, float* __restrict__ scsh)
{
    const int c = threadIdx.x;
    float s  = part2[c];
    float s2 = part2[256 + c];
    float mean = s * invM;
    float var  = fmaf(s2, invM, -mean * mean);
    float sc   = g[c] * rsqrtf(var + 1e-5f);
    scsh[c]       = sc;
    scsh[256 + c] = fmaf(-mean, sc, be[c]);
}

// ---------------------------------------------------------------------------
// In-place BN+relu+re-split on a split-half tensor. N8 = numel/8.
// ---------------------------------------------------------------------------
__global__ __launch_bounds__(256)
void bn_split_h(_Float16* __restrict__ YH, _Float16* __restrict__ YL,
                const float* __restrict__ scsh, int N8)
{
    int idx = blockIdx.x * 256 + threadIdx.x;
    const int stride = gridDim.x * 256;
    for (; idx < N8; idx += stride) {
        const size_t e0 = (size_t)idx * 8;
        const int ci0 = (int)(e0 & 255);
        half8 h = *(half8*)(YH + e0);
        half8 l = *(half8*)(YL + e0);
        float4 scA = *(const float4*)(scsh + ci0);
        float4 scB = *(const float4*)(scsh + ci0 + 4);
        float4 shA = *(const float4*)(scsh + 256 + ci0);
        float4 shB = *(const float4*)(scsh + 256 + ci0 + 4);
        float sc[8] = {scA.x, scA.y, scA.z, scA.w, scB.x, scB.y, scB.z, scB.w};
        float sh[8] = {shA.x, shA.y, shA.z, shA.w, shB.x, shB.y, shB.z, shB.w};
#pragma unroll
        for (int e = 0; e < 8; e++) {
            float v = joinf(h[e], l[e]);
            v = fmaxf(fmaf(v, sc[e], sh[e]), 0.f);
            _Float16 hh, ll;
            splitf(v, hh, ll);
            h[e] = hh;
            l[e] = ll;
        }
        *(half8*)(YH + e0) = h;
        *(half8*)(YL + e0) = l;
    }
}

// ---------------------------------------------------------------------------
// Plain fp32 -> split halves (z_e, codebook). N8 = numel/8.
// ---------------------------------------------------------------------------
__global__ __launch_bounds__(256)
void split8(const float* __restrict__ Z, _Float16* __restrict__ ZH,
            _Float16* __restrict__ ZL, int N8)
{
    int idx = blockIdx.x * 256 + threadIdx.x;
    const int stride = gridDim.x * 256;
    for (; idx < N8; idx += stride) {
        const size_t e0 = (size_t)idx * 8;
        float4 a = *(const float4*)(Z + e0);
        float4 b = *(const float4*)(Z + e0 + 4);
        float v[8] = {a.x, a.y, a.z, a.w, b.x, b.y, b.z, b.w};
        half8 h, l;
#pragma unroll
        for (int e = 0; e < 8; e++) {
            _Float16 hh, ll;
            splitf(v[e], hh, ll);
            h[e] = hh;
            l[e] = ll;
        }
        *(half8*)(ZH + e0) = h;
        *(half8*)(ZL + e0) = l;
    }
}

// w (256,256,4) [o][ci][tap] -> split halves at [o][tap*256+ci]
__global__ __launch_bounds__(256)
void prep_w_split(const float* __restrict__ w, _Float16* __restrict__ hi,
                  _Float16* __restrict__ lo)
{
    int idx = blockIdx.x * 256 + threadIdx.x;  // 262144
    int o   = idx >> 10, rem = idx & 1023;
    int tap = rem >> 8,  ci  = rem & 255;
    float v = w[((size_t)o << 10) + (ci << 2) + tap];
    _Float16 h, l;
    splitf(v, h, l);
    hi[idx] = h;
    lo[idx] = l;
}

// per-code squared norms (fp32 exact)
__global__ __launch_bounds__(256)
void prep_cnorm(const float* __restrict__ cb, float* __restrict__ cnorm)
{
    const int k = blockIdx.x;   // 1024
    const int d = threadIdx.x;  // 256
    float v = cb[((size_t)k << 8) + d];
    __shared__ float sm[256];
    sm[d] = v * v;
    __syncthreads();
    for (int off = 128; off > 0; off >>= 1) {
        if (d < off) sm[d] += sm[d + off];
        __syncthreads();
    }
    if (d == 0) cnorm[k] = sm[0];
}

// ---------------------------------------------------------------------------
// conv2..6: split-fp16 MFMA GEMM, 128x128 tile, BK=32. 4 waves in 2x2,
// wave tile 64x64. A: direct-global frags (ping-pong reg prefetch).
// B: LDS double-buffer, 1 barrier/step. K = tap*256+ci.
// Optional fused BN stats into part2 (sum @ [c], sumsq @ [256+c]).
// ---------------------------------------------------------------------------
template<int T_IN, int T_OUT, int PAD, bool STATS, bool F32OUT>
__global__ __launch_bounds__(256, 2)
void conv_gemm_mfma(const _Float16* __restrict__ XH, const _Float16* __restrict__ XL,
                    const _Float16* __restrict__ WH, const _Float16* __restrict__ WL,
                    const float* __restrict__ bias, float* __restrict__ Yf,
                    _Float16* __restrict__ YH, _Float16* __restrict__ YL,
                    float* __restrict__ part2)
{
    constexpr int M = 32 * T_OUT;
    __shared__ _Float16 BsH[2][4096], BsL[2][4096];
    __shared__ float chS[128], chS2[128];

    const int tid  = threadIdx.x;
    const int lane = tid & 63;
    const int wv   = tid >> 6;
    const int wr   = wv >> 1, wc = wv & 1;
    const int fr   = lane & 15, kgf = lane >> 4;
    const int m0 = blockIdx.y * 128;
    const int n0 = blockIdx.x * 128;

    // B staging: thread -> row rB, 2 granules at su0, su0+8 (halves)
    const int rB   = tid >> 1;
    const int su0  = (tid & 1) << 4;
    const int swzB = (rB & 7) << 3;
    const int bD0  = (rB * 32 + su0) ^ swzB;
    const int bD1  = (rB * 32 + su0 + 8) ^ swzB;
    const size_t bSrcRow = ((size_t)(n0 + rB)) << 10;

    // B fragment base (full-address XOR, row&7 == fr&7)
    const int hbB = ((wc * 64 + fr) * 32 + kgf * 8) ^ ((fr & 7) << 3);

    // A rows (wave-private): row = m0 + wr*64 + g*16 + fr
    long long aAddr[4]; int tG[4]; bool mOK[4];
#pragma unroll
    for (int g = 0; g < 4; g++) {
        int row = m0 + wr * 64 + g * 16 + fr;
        bool ok = row < M;
        int rr = ok ? row : 0;
        int b;
        if (T_OUT == 4096) b = rr >> 12;
        else               b = (rr - (rr >> 12)) >> 12;   // rr/4097
        int t = rr - b * T_OUT;
        mOK[g] = ok; tG[g] = t;
        aAddr[g] = (((long long)b * T_IN + t) << 8) + kgf * 8;
    }

    const half8 hz = {(_Float16)0, (_Float16)0, (_Float16)0, (_Float16)0,
                      (_Float16)0, (_Float16)0, (_Float16)0, (_Float16)0};

    f32x4 acc1[4][4], acc2[4][4];
#pragma unroll
    for (int g = 0; g < 4; g++)
#pragma unroll
        for (int j = 0; j < 4; j++) {
            acc1[g][j] = (f32x4){0.f, 0.f, 0.f, 0.f};
            acc2[g][j] = (f32x4){0.f, 0.f, 0.f, 0.f};
        }

    half8 a0H[4], a0L[4], a1H[4], a1L[4];

    auto loadA = [&](int s, half8* dH, half8* dL) {
        const int tap = s >> 3;
        const int ci0 = (s & 7) << 5;
        const int dt  = tap - PAD;
#pragma unroll
        for (int g = 0; g < 4; g++) {
            const int ti = tG[g] + dt;
            if (mOK[g] && ti >= 0 && ti < T_IN) {
                const long long ga = aAddr[g] + ((long long)dt << 8) + ci0;
                dH[g] = *(const half8*)(XH + ga);
                dL[g] = *(const half8*)(XL + ga);
            } else {
                dH[g] = hz;
                dL[g] = hz;
            }
        }
    };

    auto body = [&](int s, half8* aUH, half8* aUL, half8* aNH, half8* aNL) {
        const int cur = s & 1;
        const bool more = (s < 31);
        half8 bRH0, bRH1, bRL0, bRL1;
        if (more) {
            const size_t gb = bSrcRow + (size_t)(s + 1) * 32 + su0;
            bRH0 = *(const half8*)(WH + gb);
            bRH1 = *(const half8*)(WH + gb + 8);
            bRL0 = *(const half8*)(WL + gb);
            bRL1 = *(const half8*)(WL + gb + 8);
            loadA(s + 1, aNH, aNL);
        }
#pragma unroll
        for (int j = 0; j < 4; j++) {
            half8 bh = *(const half8*)&BsH[cur][hbB + j * 512];
            half8 bl = *(const half8*)&BsL[cur][hbB + j * 512];
#pragma unroll
            for (int g = 0; g < 4; g++) {
                acc1[g][j] = MFMA16(aUH[g], bh, acc1[g][j]);
                acc2[g][j] = MFMA16(aUH[g], bl, acc2[g][j]);
                acc2[g][j] = MFMA16(aUL[g], bh, acc2[g][j]);
            }
        }
        if (more) {
            *(half8*)&BsH[cur ^ 1][bD0] = bRH0;
            *(half8*)&BsH[cur ^ 1][bD1] = bRH1;
            *(half8*)&BsL[cur ^ 1][bD0] = bRL0;
            *(half8*)&BsL[cur ^ 1][bD1] = bRL1;
        }
        __syncthreads();
    };

    // prologue: B(0) -> buf0, A(0) -> set0
    {
        const size_t gb = bSrcRow + su0;
        *(half8*)&BsH[0][bD0] = *(const half8*)(WH + gb);
        *(half8*)&BsH[0][bD1] = *(const half8*)(WH + gb + 8);
        *(half8*)&BsL[0][bD0] = *(const half8*)(WL + gb);
        *(half8*)&BsL[0][bD1] = *(const half8*)(WL + gb + 8);
    }
    loadA(0, a0H, a0L);
    __syncthreads();

    for (int sp = 0; sp < 32; sp += 2) {
        body(sp,     a0H, a0L, a1H, a1L);
        body(sp + 1, a1H, a1L, a0H, a0L);
    }

    // ---- epilogue: C = acc1 + acc2/2048 + bias (+ fused BN stats) ----
    if constexpr (STATS) {
        if (tid < 128) { chS[tid] = 0.f; chS2[tid] = 0.f; }
        __syncthreads();
    }
    float bj[4];
#pragma unroll
    for (int j = 0; j < 4; j++) bj[j] = bias[n0 + wc * 64 + j * 16 + fr];
    float js[4] = {0.f, 0.f, 0.f, 0.f}, js2[4] = {0.f, 0.f, 0.f, 0.f};
#pragma unroll
    for (int g = 0; g < 4; g++)
#pragma unroll
        for (int q = 0; q < 4; q++) {
            const int row = m0 + wr * 64 + g * 16 + kgf * 4 + q;
            if (row < M) {
#pragma unroll
                for (int j = 0; j < 4; j++) {
                    float vv = acc1[g][j][q] + acc2[g][j][q] * INV2048 + bj[j];
                    const size_t o = ((size_t)row << 8) + n0 + wc * 64 + j * 16 + fr;
                    if constexpr (F32OUT) {
                        Yf[o] = vv;
                    } else {
                        _Float16 h, l;
                        splitf(vv, h, l);
                        YH[o] = h;
                        YL[o] = l;
                    }
                    if constexpr (STATS) {
                        js[j] += vv;
                        js2[j] = fmaf(vv, vv, js2[j]);
                    }
                }
            }
        }
    if constexpr (STATS) {
#pragma unroll
        for (int j = 0; j < 4; j++) {
            atomicAdd(&chS[wc * 64 + j * 16 + fr], js[j]);
            atomicAdd(&chS2[wc * 64 + j * 16 + fr], js2[j]);
        }
        __syncthreads();
        if (tid < 128) {
            atomicAdd(&part2[n0 + tid], chS[tid]);
            atomicAdd(&part2[256 + n0 + tid], chS2[tid]);
        }
    }
}

// ---------------------------------------------------------------------------
// VQ argmin: same 2x2-wave geometry. A (z rows) direct-global, B (codebook)
// LDS double-buffered. 64 flat steps (8 code tiles x 8 d-steps).
// ---------------------------------------------------------------------------
__global__ __launch_bounds__(256, 2)
void vq_argmin_mfma(const _Float16* __restrict__ ZH, const _Float16* __restrict__ ZL,
                    const _Float16* __restrict__ CH, const _Float16* __restrict__ CL,
                    const float* __restrict__ cnorm, int* __restrict__ ids)
{
    __shared__ _Float16 BsH[2][4096], BsL[2][4096];
    __shared__ float rv[2][128];
    __shared__ int   ri[2][128];

    const int tid  = threadIdx.x;
    const int lane = tid & 63;
    const int wv   = tid >> 6;
    const int wr   = wv >> 1, wc = wv & 1;
    const int fr   = lane & 15, kgf = lane >> 4;
    const int m0 = blockIdx.x * 128;

    const int rB   = tid >> 1;
    const int su0  = (tid & 1) << 4;
    const int swzB = (rB & 7) << 3;
    const int bD0  = (rB * 32 + su0) ^ swzB;
    const int bD1  = (rB * 32 + su0 + 8) ^ swzB;

    const int hbB = ((wc * 64 + fr) * 32 + kgf * 8) ^ ((fr & 7) << 3);

    size_t aAddr[4];
#pragma unroll
    for (int g = 0; g < 4; g++)
        aAddr[g] = (((size_t)(m0 + wr * 64 + g * 16 + fr)) << 8) + kgf * 8;

    f32x4 acc1[4][4], acc2[4][4];
    half8 a0H[4], a0L[4], a1H[4], a1L[4];

    float bv[4][4];
    int   bk[4][4];
#pragma unroll
    for (int g = 0; g < 4; g++)
#pragma unroll
        for (int q = 0; q < 4; q++) { bv[g][q] = 3.4e38f; bk[g][q] = 0; }

    auto loadA = [&](int s, half8* dH, half8* dL) {
        const int dd = (s & 7) << 5;
#pragma unroll
        for (int g = 0; g < 4; g++) {
            const size_t ga = aAddr[g] + dd;
            dH[g] = *(const half8*)(ZH + ga);
            dL[g] = *(const half8*)(ZL + ga);
        }
    };

    auto body = [&](int s, half8* aUH, half8* aUL, half8* aNH, half8* aNL) {
        const int cur = s & 1;
        const bool more = (s < 63);
        half8 bRH0, bRH1, bRL0, bRL1;
        if (more) {
            const int s1 = s + 1;
            const size_t gb = (((size_t)(((s1 >> 3) << 7) + rB)) << 8)
                              + ((s1 & 7) << 5) + su0;
            bRH0 = *(const half8*)(CH + gb);
            bRH1 = *(const half8*)(CH + gb + 8);
            bRL0 = *(const half8*)(CL + gb);
            bRL1 = *(const half8*)(CL + gb + 8);
            loadA(s1, aNH, aNL);
        }
#pragma unroll
        for (int j = 0; j < 4; j++) {
            half8 bh = *(const half8*)&BsH[cur][hbB + j * 512];
            half8 bl = *(const half8*)&BsL[cur][hbB + j * 512];
#pragma unroll
            for (int g = 0; g < 4; g++) {
                acc1[g][j] = MFMA16(aUH[g], bh, acc1[g][j]);
                acc2[g][j] = MFMA16(aUH[g], bl, acc2[g][j]);
                acc2[g][j] = MFMA16(aUL[g], bh, acc2[g][j]);
            }
        }
        if (more) {
            *(half8*)&BsH[cur ^ 1][bD0] = bRH0;
            *(half8*)&BsH[cur ^ 1][bD1] = bRH1;
            *(half8*)&BsL[cur ^ 1][bD0] = bRL0;
            *(half8*)&BsL[cur ^ 1][bD1] = bRL1;
        }
        __syncthreads();
    };

    // prologue
    {
        const size_t gb = (((size_t)rB) << 8) + su0;
        *(half8*)&BsH[0][bD0] = *(const half8*)(CH + gb);
        *(half8*)&BsH[0][bD1] = *(const half8*)(CH + gb + 8);
        *(half8*)&BsL[0][bD0] = *(const half8*)(CL + gb);
        *(half8*)&BsL[0][bD1] = *(const half8*)(CL + gb + 8);
    }
    loadA(0, a0H, a0L);
    __syncthreads();

    for (int nt = 0; nt < 8; nt++) {
#pragma unroll
        for (int g = 0; g < 4; g++)
#pragma unroll
            for (int j = 0; j < 4; j++) {
                acc1[g][j] = (f32x4){0.f, 0.f, 0.f, 0.f};
                acc2[g][j] = (f32x4){0.f, 0.f, 0.f, 0.f};
            }
        for (int sp = 0; sp < 8; sp += 2) {
            const int s = nt * 8 + sp;
            body(s,     a0H, a0L, a1H, a1L);
            body(s + 1, a1H, a1L, a0H, a0L);
        }
        // running min for this 128-code tile
#pragma unroll
        for (int j = 0; j < 4; j++) {
            const int code = nt * 128 + wc * 64 + j * 16 + fr;
            const float cn = cnorm[code];
#pragma unroll
            for (int g = 0; g < 4; g++)
#pragma unroll
                for (int q = 0; q < 4; q++) {
                    float sscore = fmaf(-2.f, acc1[g][j][q] + acc2[g][j][q] * INV2048, cn);
                    if (sscore < bv[g][q] || (sscore == bv[g][q] && code < bk[g][q])) {
                        bv[g][q] = sscore; bk[g][q] = code;
                    }
                }
        }
    }

    // reduce across fr lanes (codes differ by fr), then across wc via LDS
#pragma unroll
    for (int g = 0; g < 4; g++)
#pragma unroll
        for (int q = 0; q < 4; q++) {
            float v = bv[g][q];
            int   k = bk[g][q];
            for (int msk = 1; msk < 16; msk <<= 1) {
                float ov = __shfl_xor(v, msk, 64);
                int   ok = __shfl_xor(k, msk, 64);
                if (ov < v || (ov == v && ok < k)) { v = ov; k = ok; }
            }
            if (fr == 0) {
                const int rloc = wr * 64 + g * 16 + kgf * 4 + q;
                rv[wc][rloc] = v;
                ri[wc][rloc] = k;
            }
        }
    __syncthreads();
    if (tid < 128) {
        float v0 = rv[0][tid]; int k0 = ri[0][tid];
        float v1 = rv[1][tid]; int k1 = ri[1][tid];
        ids[m0 + tid] = (v1 < v0 || (v1 == v0 && k1 < k0)) ? k1 : k0;
    }
}

// ---------------------------------------------------------------------------
// Counting sort with LDS-privatized histograms.
// ---------------------------------------------------------------------------
__global__ __launch_bounds__(256)
void vq_hist(const int* __restrict__ ids, unsigned* __restrict__ cnt)
{
    __shared__ unsigned lc[1024];
    const int t = threadIdx.x;
#pragma unroll
    for (int u = 0; u < 4; u++) lc[t + 256 * u] = 0u;
    __syncthreads();
    const int m = blockIdx.x * 256 + t;
    atomicAdd(&lc[ids[m]], 1u);
    __syncthreads();
#pragma unroll
    for (int u = 0; u < 4; u++) {
        const int c = t + 256 * u;
        const unsigned h = lc[c];
        if (h) atomicAdd(&cnt[c], h);
    }
}

__global__ __launch_bounds__(1024)
void vq_scan(const unsigned* __restrict__ cnt, int* __restrict__ offs, int* __restrict__ curs)
{
    __shared__ int sm[1024];
    const int k = threadIdx.x;
    const int c = (int)cnt[k];
    sm[k] = c;
    __syncthreads();
    for (int off = 1; off < 1024; off <<= 1) {
        int v = (k >= off) ? sm[k - off] : 0;
        __syncthreads();
        sm[k] += v;
        __syncthreads();
    }
    int exc = sm[k] - c;
    offs[k] = exc;
    curs[k] = exc;
    if (k == 1023) offs[1024] = sm[k];
}

__global__ __launch_bounds__(256)
void vq_scatter(const int* __restrict__ ids, int* __restrict__ curs,
                int* __restrict__ perm, int* __restrict__ scode)
{
    __shared__ int lcnt[1024];
    __shared__ int lbase[1024];
    const int t = threadIdx.x;
#pragma unroll
    for (int u = 0; u < 4; u++) lcnt[t + 256 * u] = 0;
    __syncthreads();
    const int m = blockIdx.x * 256 + t;
    const int id = ids[m];
    const int lrank = atomicAdd(&lcnt[id], 1);
    __syncthreads();
#pragma unroll
    for (int u = 0; u < 4; u++) {
        const int c = t + 256 * u;
        const int h = lcnt[c];
        if (h) lbase[c] = atomicAdd(&curs[c], h);
    }
    __syncthreads();
    const int pos = lbase[id] + lrank;
    perm[pos]  = m;
    scode[pos] = id;
}

__global__ __launch_bounds__(256)
void vq_gather_zq(const int* __restrict__ ids, const float* __restrict__ cb,
                  float* __restrict__ zq)
{
    const int row = blockIdx.x * 4 + (threadIdx.x >> 6);
    const int d4  = (threadIdx.x & 63) << 2;
    const int id  = ids[row];
    *(float4*)(zq + ((size_t)row << 8) + d4) =
        *(const float4*)(cb + ((size_t)id << 8) + d4);
}

__global__ __launch_bounds__(256)
void vq_segsum(const int* __restrict__ perm, const int* __restrict__ scode,
               const float* __restrict__ Z, float* __restrict__ sums)
{
    __shared__ int pm[256];
    __shared__ int cd[256];
    const int p0 = blockIdx.x * 256;
    const int d  = threadIdx.x;
    pm[d] = perm[p0 + d];
    cd[d] = scode[p0 + d];
    __syncthreads();
    float s = 0.f;
    int cur = cd[0];
    for (int i = 0; i < 256; i++) {
        int c = cd[i];
        float v = Z[((size_t)pm[i] << 8) + d];
        if (c != cur) {
            atomicAdd(&sums[((size_t)cur << 8) + d], s);
            s = 0.f;
            cur = c;
        }
        s += v;
    }
    atomicAdd(&sums[((size_t)cur << 8) + d], s);
}

__global__ __launch_bounds__(1024)
void vq_fin1(const unsigned* __restrict__ cnt, const float* __restrict__ ema_cs,
             float* __restrict__ ecs, float* __restrict__ nval)
{
    __shared__ float sm[1024];
    const int k = threadIdx.x;
    float e = fmaf(ema_cs[k], 0.99f, 0.01f * (float)cnt[k]);
    ecs[k] = e;
    sm[k] = e;
    __syncthreads();
    for (int off = 512; off > 0; off >>= 1) {
        if (k < off) sm[k] += sm[k + off];
        __syncthreads();
    }
    if (k == 0) nval[0] = sm[0];
}

__global__ __launch_bounds__(256)
void vq_fin2(const float* __restrict__ ema_w, const float* __restrict__ sums,
             const float* __restrict__ ecs, const float* __restrict__ nval,
             float* __restrict__ cbout)
{
    const int k = blockIdx.x, d = threadIdx.x;
    const float n = nval[0];
    const float sm = ((ecs[k] + 1e-5f) / (n + 0.01024f)) * n;
    const size_t idx = ((size_t)k << 8) + d;
    cbout[idx] = fmaf(ema_w[idx], 0.99f, 0.01f * sums[idx]) / sm;
}

// ===========================================================================
extern "C" void kernel_launch(void* const* d_in, const int* in_sizes, int n_in,
                              void* d_out, int out_size, void* d_ws, size_t ws_size,
                              hipStream_t stream)
{
    (void)in_sizes; (void)n_in; (void)out_size; (void)ws_size;

    const float* x = (const float*)d_in[0];
    const float* w[7]; const float* bias[7];
    for (int i = 1; i <= 6; i++) {
        w[i]    = (const float*)d_in[1 + 2 * (i - 1)];
        bias[i] = (const float*)d_in[2 + 2 * (i - 1)];
    }
    const float* g[6]; const float* be[6];
    for (int i = 1; i <= 5; i++) {
        g[i]  = (const float*)d_in[13 + 2 * (i - 1)];
        be[i] = (const float*)d_in[14 + 2 * (i - 1)];
    }
    const float* codebook = (const float*)d_in[23];
    const float* ema_w    = (const float*)d_in[24];
    const float* ema_cs   = (const float*)d_in[25];

    float* out   = (float*)d_out;
    float* z_e   = out;                      // 32*4096*256
    float* z_q   = out + 33554432;           // 32*4096*256
    float* cbout = out + 67108864;           // 1024*256
    float* ecs   = out + 67371008;           // 1024

    // ping pair (4097-sized layers) in ws; pong pair (4096-sized) in z_q region
    float* ws = (float*)d_ws;
    _Float16* pingH = (_Float16*)ws;             // 131104*256 = 33,562,624 halves
    _Float16* pingL = pingH + 33562624;
    _Float16* pongH = (_Float16*)z_q;            // 131072*256 halves (exact fit)
    _Float16* pongL = pongH + 33554432;

    float* wsf   = ws + 33562624;                // after ping pair
    _Float16* wthi = (_Float16*)wsf;             // 5*262144 halves (655,360 fl)
    _Float16* wtlo = (_Float16*)(wsf + 655360);  // 5*262144 halves
    _Float16* cbhi = (_Float16*)(wsf + 1310720); // 262144 halves (131,072 fl)
    _Float16* cblo = (_Float16*)(wsf + 1441792); // 262144 halves
    float* cnorm = wsf + 1572864;                // 1024
    float* scsh  = cnorm + 1024;                 // 5 * 512
    float* part  = scsh + 2560;                  // 2 * 65536 (layer-1 BN partials)
    float* sums  = part + 131072;                // 262144
    float* nval  = sums + 262144;                // 16
    int*      ids  = (int*)(nval + 16);          // 131072
    unsigned* cnt  = (unsigned*)(ids + 131072);  // 1024
    int*      offs = (int*)(cnt + 1024);         // 1025
    int*      curs = offs + 1025;                // 1024
    int*      perm = curs + 1024;                // 131072
    int*      scode = (int*)part;                // reuse BN partial region
    float*    part2 = (float*)(perm + 131072);   // 4 layers * 512 fused BN stats

    hipMemsetAsync(cnt, 0, 1024 * sizeof(unsigned), stream);
    hipMemsetAsync(sums, 0, 262144 * sizeof(float), stream);
    hipMemsetAsync(part2, 0, 2048 * sizeof(float), stream);

    // prep: split weights ([o][tap*256+ci]) + codebook + cnorm
    for (int i = 0; i < 5; i++)
        prep_w_split<<<1024, 256, 0, stream>>>(w[i + 2], wthi + (size_t)i * 262144,
                                               wtlo + (size_t)i * 262144);
    split8<<<128, 256, 0, stream>>>(codebook, cbhi, cblo, 32768);
    prep_cnorm<<<1024, 256, 0, stream>>>(codebook, cnorm);

    // layer 1: x -> ping halves (T=4097); deterministic BN stats path
    conv1_kernel<<<dim3(129, 32), 256, 0, stream>>>(x, w[1], bias[1], pingH, pingL);
    bn_partial_h<<<256, 256, 0, stream>>>(pingH, pingL, 131104, part);
    bn_finalize<<<1, 256, 0, stream>>>(part, g[1], be[1], 1.f / 131104.f, scsh);
    bn_split_h<<<4096, 256, 0, stream>>>(pingH, pingL, scsh, 131104 * 32);

    // layer 2: ping -> pong (fused stats -> part2+0)
    conv_gemm_mfma<4097, 4096, 1, true, false><<<dim3(2, 1024), 256, 0, stream>>>(
        pingH, pingL, wthi, wtlo, bias[2], nullptr, pongH, pongL, part2);
    bn_finalize2<<<1, 256, 0, stream>>>(part2, g[2], be[2], 1.f / 131072.f, scsh + 512);
    bn_split_h<<<4096, 256, 0, stream>>>(pongH, pongL, scsh + 512, 131072 * 32);

    // layer 3: pong -> ping (fused stats -> part2+512)
    conv_gemm_mfma<4096, 4097, 2, true, false><<<dim3(2, 1025), 256, 0, stream>>>(
        pongH, pongL, wthi + 262144, wtlo + 262144, bias[3], nullptr, pingH, pingL,
        part2 + 512);
    bn_finalize2<<<1, 256, 0, stream>>>(part2 + 512, g[3], be[3], 1.f / 131104.f, scsh + 1024);
    bn_split_h<<<4096, 256, 0, stream>>>(pingH, pingL, scsh + 1024, 131104 * 32);

    // layer 4: ping -> pong (fused stats -> part2+1024)
    conv_gemm_mfma<4097, 4096, 1, true, false><<<dim3(2, 1024), 256, 0, stream>>>(
        pingH, pingL, wthi + 524288, wtlo + 524288, bias[4], nullptr, pongH, pongL,
        part2 + 1024);
    bn_finalize2<<<1, 256, 0, stream>>>(part2 + 1024, g[4], be[4], 1.f / 131072.f, scsh + 1536);
    bn_split_h<<<4096, 256, 0, stream>>>(pongH, pongL, scsh + 1536, 131072 * 32);

    // layer 5: pong -> ping (fused stats -> part2+1536)
    conv_gemm_mfma<4096, 4097, 2, true, false><<<dim3(2, 1025), 256, 0, stream>>>(
        pongH, pongL, wthi + 786432, wtlo + 786432, bias[5], nullptr, pingH, pingL,
        part2 + 1536);
    bn_finalize2<<<1, 256, 0, stream>>>(part2 + 1536, g[5], be[5], 1.f / 131104.f, scsh + 2048);
    bn_split_h<<<4096, 256, 0, stream>>>(pingH, pingL, scsh + 2048, 131104 * 32);

    // layer 6: ping -> z_e (fp32 out, no BN/relu, no stats)
    conv_gemm_mfma<4097, 4096, 1, false, true><<<dim3(2, 1024), 256, 0, stream>>>(
        pingH, pingL, wthi + 1048576, wtlo + 1048576, bias[6], z_e, nullptr, nullptr,
        nullptr);

    // VQ
    split8<<<4096, 256, 0, stream>>>(z_e, pongH, pongL, 4194304);
    vq_argmin_mfma<<<1024, 256, 0, stream>>>(pongH, pongL, cbhi, cblo, cnorm, ids);
    vq_hist<<<512, 256, 0, stream>>>(ids, cnt);
    vq_scan<<<1, 1024, 0, stream>>>(cnt, offs, curs);
    vq_scatter<<<512, 256, 0, stream>>>(ids, curs, perm, scode);
    vq_gather_zq<<<32768, 256, 0, stream>>>(ids, codebook, z_q);
    vq_segsum<<<512, 256, 0, stream>>>(perm, scode, z_e, sums);
    vq_fin1<<<1, 1024, 0, stream>>>(cnt, ema_cs, ecs, nval);
    vq_fin2<<<1024, 256, 0, stream>>>(ema_w, sums, ecs, nval, cbout);
}